// Round 1
// baseline (952.105 us; speedup 1.0000x reference)
//
#include <hip/hip_runtime.h>
#include <math.h>

#define N_NODES 100000
#define N_EDGES 1600000
#define HID 128
#define OUTD 47
#define OSTR 48

// ---------------- CSR build ----------------

__global__ void count_k(const int* __restrict__ dst, int* __restrict__ cnt) {
    int e = blockIdx.x * 256 + threadIdx.x;
    if (e < N_EDGES) atomicAdd(&cnt[dst[e]], 1);
}

__global__ void dinv_k(const int* __restrict__ cnt, float* __restrict__ dinv) {
    int i = blockIdx.x * 256 + threadIdx.x;
    if (i < N_NODES) dinv[i] = rsqrtf((float)(cnt[i] + 1));  // +1 self-loop
}

__global__ void scan1_k(const int* __restrict__ cnt, int* __restrict__ rowptr,
                        int* __restrict__ bsum) {
    __shared__ int s[256];
    int t = threadIdx.x;
    int i = blockIdx.x * 256 + t;
    int v = (i < N_NODES) ? cnt[i] : 0;
    s[t] = v; __syncthreads();
    for (int off = 1; off < 256; off <<= 1) {
        int x = (t >= off) ? s[t - off] : 0;
        __syncthreads();
        s[t] += x;
        __syncthreads();
    }
    if (i < N_NODES) rowptr[i] = s[t] - v;   // exclusive
    if (t == 255) bsum[blockIdx.x] = s[t];   // block total
}

__global__ void scan2_k(int* __restrict__ bsum, int nb) {
    __shared__ int s[512];
    int t = threadIdx.x;
    int v = (t < nb) ? bsum[t] : 0;
    s[t] = v; __syncthreads();
    for (int off = 1; off < 512; off <<= 1) {
        int x = (t >= off) ? s[t - off] : 0;
        __syncthreads();
        s[t] += x;
        __syncthreads();
    }
    if (t < nb) bsum[t] = s[t] - v;          // exclusive block offsets
}

__global__ void scan3_k(int* __restrict__ rowptr, const int* __restrict__ bsum) {
    int i = blockIdx.x * 256 + threadIdx.x;
    if (i < N_NODES) rowptr[i] += bsum[blockIdx.x];
    if (i == 0) rowptr[N_NODES] = N_EDGES;
}

__global__ void fill_k(const int* __restrict__ src, const int* __restrict__ dst,
                       const int* __restrict__ rowptr, int* __restrict__ fillc,
                       int* __restrict__ colv) {
    int e = blockIdx.x * 256 + threadIdx.x;
    if (e < N_EDGES) {
        int d = dst[e];
        int p = atomicAdd(&fillc[d], 1);
        colv[rowptr[d] + p] = src[e];
    }
}

// ---------------- GEMM (K=128 fixed), fused BN+ReLU on A-load, dinv prescale epilogue ----------------
// MODE 0: A plain.  MODE 1: A' = relu(A*s + t) elementwise per K-channel.

template <int MODE>
__global__ __launch_bounds__(256, 2) void gemm_k(
    const float* __restrict__ A, const float* __restrict__ W,
    const float* __restrict__ bns, const float* __restrict__ bnt,
    const float* __restrict__ dinv, float* __restrict__ Out,
    int ncols, int ostride)
{
    __shared__ float As[8][132];
    __shared__ float Bs[8][132];
    __shared__ float sS[128], sT[128];

    int t = threadIdx.x;
    if (MODE == 1) {
        if (t < 128) { sS[t] = bns[t]; sT[t] = bnt[t]; }
        __syncthreads();
    }
    int rowTile = blockIdx.x * 128;
    int ty = t >> 4, tx = t & 15;          // compute: rows ty*8+i, cols tx*8+j
    int lrow = t >> 1, half = t & 1;       // A-load: 2 threads/row, float4 each
    int gr = rowTile + lrow;
    bool rv = (gr < N_NODES);
    const float* Aptr = A + (size_t)gr * 128 + half * 4;
    int bk = t >> 5;                       // B-load: k row 0..7
    int bc = (t & 31) * 4;                 // col group

    float acc[8][8];
#pragma unroll
    for (int i = 0; i < 8; i++)
#pragma unroll
        for (int j = 0; j < 8; j++) acc[i][j] = 0.f;

    for (int kk = 0; kk < 128; kk += 8) {
        float4 av = make_float4(0.f, 0.f, 0.f, 0.f);
        if (rv) av = *(const float4*)(Aptr + kk);
        if (MODE == 1) {
            int kb = kk + half * 4;
            av.x = fmaxf(av.x * sS[kb + 0] + sT[kb + 0], 0.f);
            av.y = fmaxf(av.y * sS[kb + 1] + sT[kb + 1], 0.f);
            av.z = fmaxf(av.z * sS[kb + 2] + sT[kb + 2], 0.f);
            av.w = fmaxf(av.w * sS[kb + 3] + sT[kb + 3], 0.f);
        }
        As[half * 4 + 0][lrow] = av.x;
        As[half * 4 + 1][lrow] = av.y;
        As[half * 4 + 2][lrow] = av.z;
        As[half * 4 + 3][lrow] = av.w;
#pragma unroll
        for (int i = 0; i < 4; i++) {
            int c = bc + i;
            Bs[bk][c] = (c < ncols) ? W[(kk + bk) * ncols + c] : 0.f;
        }
        __syncthreads();
#pragma unroll
        for (int k = 0; k < 8; k++) {
            float a[8], b[8];
#pragma unroll
            for (int i = 0; i < 8; i++) a[i] = As[k][ty * 8 + i];
#pragma unroll
            for (int j = 0; j < 8; j++) b[j] = Bs[k][tx * 8 + j];
#pragma unroll
            for (int i = 0; i < 8; i++)
#pragma unroll
                for (int j = 0; j < 8; j++) acc[i][j] = fmaf(a[i], b[j], acc[i][j]);
        }
        __syncthreads();
    }

#pragma unroll
    for (int i = 0; i < 8; i++) {
        int r = rowTile + ty * 8 + i;
        if (r < N_NODES) {
            float d = dinv[r];
#pragma unroll
            for (int j = 0; j < 8; j++) {
                int c = tx * 8 + j;
                if (c < ncols) Out[(size_t)r * ostride + c] = acc[i][j] * d;
            }
        }
    }
}

// ---------------- Aggregation: one wave per dst node, 128-wide (float2/lane) ----------------

__global__ __launch_bounds__(256) void agg_k(
    const float* __restrict__ Hp, const int* __restrict__ rowptr,
    const int* __restrict__ colv, const float* __restrict__ dinv,
    const float* __restrict__ bias, float* __restrict__ out)
{
    int gw = (blockIdx.x * 256 + threadIdx.x) >> 6;
    int lane = threadIdx.x & 63;
    if (gw >= N_NODES) return;
    int rp = rowptr[gw], re = rowptr[gw + 1];
    const float2* H2 = (const float2*)Hp;
    float2 acc = H2[gw * 64 + lane];   // self-loop (prescaled row)
    for (int j0 = rp; j0 < re; j0 += 64) {
        int idx = 0;
        if (j0 + lane < re) idx = colv[j0 + lane];
        int n = min(64, re - j0);
        int j = 0;
        for (; j + 1 < n; j += 2) {
            int s0 = __shfl(idx, j);
            int s1 = __shfl(idx, j + 1);
            float2 v0 = H2[s0 * 64 + lane];
            float2 v1 = H2[s1 * 64 + lane];
            acc.x += v0.x + v1.x;
            acc.y += v0.y + v1.y;
        }
        if (j < n) {
            int s0 = __shfl(idx, j);
            float2 v0 = H2[s0 * 64 + lane];
            acc.x += v0.x;
            acc.y += v0.y;
        }
    }
    float d = dinv[gw];
    float2 b = ((const float2*)bias)[lane];
    float2 r;
    r.x = acc.x * d + b.x;
    r.y = acc.y * d + b.y;
    ((float2*)out)[gw * 64 + lane] = r;
}

// ---------------- Final aggregation (47-wide) + bias + log_softmax ----------------

__global__ __launch_bounds__(256) void agg_out_k(
    const float* __restrict__ Hp, const int* __restrict__ rowptr,
    const int* __restrict__ colv, const float* __restrict__ dinv,
    const float* __restrict__ b2, float* __restrict__ out)
{
    int gw = (blockIdx.x * 256 + threadIdx.x) >> 6;
    int lane = threadIdx.x & 63;
    if (gw >= N_NODES) return;
    bool act = lane < OUTD;
    int rp = rowptr[gw], re = rowptr[gw + 1];
    float acc = act ? Hp[gw * OSTR + lane] : 0.f;
    for (int j0 = rp; j0 < re; j0 += 64) {
        int idx = 0;
        if (j0 + lane < re) idx = colv[j0 + lane];
        int n = min(64, re - j0);
        for (int j = 0; j < n; j++) {
            int s = __shfl(idx, j);
            if (act) acc += Hp[s * OSTR + lane];
        }
    }
    float v = acc * dinv[gw] + (act ? b2[lane] : 0.f);
    float m = act ? v : -INFINITY;
    for (int off = 32; off; off >>= 1) m = fmaxf(m, __shfl_xor(m, off));
    float ex = act ? expf(v - m) : 0.f;
    float sum = ex;
    for (int off = 32; off; off >>= 1) sum += __shfl_xor(sum, off);
    if (act) out[(size_t)gw * OUTD + lane] = v - m - logf(sum);
}

// ---------------- BatchNorm stats ----------------

__global__ __launch_bounds__(256) void bnstats_k(const float* __restrict__ H,
                                                 float* __restrict__ sum,
                                                 float* __restrict__ sq)
{
    __shared__ float ls[256], lq[256];
    int t = threadIdx.x;
    int idx = blockIdx.x * 256 + t;
    int stride = gridDim.x * 256;            // multiple of 128 -> channel = t & 127
    float s = 0.f, q = 0.f;
    for (; idx < N_NODES * 128; idx += stride) {
        float v = H[idx];
        s += v;
        q += v * v;
    }
    ls[t] = s; lq[t] = q; __syncthreads();
    if (t < 128) {
        atomicAdd(&sum[t], ls[t] + ls[t + 128]);
        atomicAdd(&sq[t],  lq[t] + lq[t + 128]);
    }
}

__global__ void bnfinal_k(const float* __restrict__ sum, const float* __restrict__ sq,
                          const float* __restrict__ g, const float* __restrict__ be,
                          float* __restrict__ bs, float* __restrict__ bt)
{
    int c = threadIdx.x;
    if (c < 128) {
        float mean = sum[c] * (1.0f / N_NODES);
        float var = sq[c] * (1.0f / N_NODES) - mean * mean;
        float inv = rsqrtf(var + 1e-5f);
        float s = g[c] * inv;
        bs[c] = s;
        bt[c] = be[c] - mean * s;
    }
}

// ---------------- launch ----------------

extern "C" void kernel_launch(void* const* d_in, const int* in_sizes, int n_in,
                              void* d_out, int out_size, void* d_ws, size_t ws_size,
                              hipStream_t stream)
{
    const float* x   = (const float*)d_in[0];
    const int*   ei  = (const int*)d_in[1];
    const float* W0  = (const float*)d_in[2];
    const float* b0  = (const float*)d_in[3];
    const float* W1  = (const float*)d_in[4];
    const float* b1  = (const float*)d_in[5];
    const float* W2  = (const float*)d_in[6];
    const float* b2  = (const float*)d_in[7];
    const float* g0  = (const float*)d_in[8];
    const float* be0 = (const float*)d_in[9];
    const float* g1  = (const float*)d_in[10];
    const float* be1 = (const float*)d_in[11];
    const int* srcv = ei;
    const int* dstv = ei + N_EDGES;

    char* w = (char*)d_ws;
    float* H0 = (float*)w;      w += (size_t)N_NODES * 128 * 4;
    float* H1 = (float*)w;      w += (size_t)N_NODES * 128 * 4;
    int* cnt  = (int*)w;        w += (size_t)N_NODES * 4;
    int* fillc = (int*)w;       w += (size_t)N_NODES * 4;
    int* rowptr = (int*)w;      w += (size_t)(N_NODES + 1) * 4;
    int* colv = (int*)w;        w += (size_t)N_EDGES * 4;
    float* dinv = (float*)w;    w += (size_t)N_NODES * 4;
    int* bsum = (int*)w;        w += 512 * 4;
    float* bnS = (float*)w;     w += 128 * 4;
    float* bnQ = (float*)w;     w += 128 * 4;
    float* bns = (float*)w;     w += 128 * 4;
    float* bnt = (float*)w;     w += 128 * 4;

    int eb = (N_EDGES + 255) / 256;   // 6250
    int nb = (N_NODES + 255) / 256;   // 391
    int gb = (N_NODES + 127) / 128;   // 782
    int ab = (N_NODES * 64 + 255) / 256;  // 25000

    hipMemsetAsync(cnt, 0, (size_t)N_NODES * 4 * 2, stream);  // cnt + fillc (contiguous)

    count_k<<<eb, 256, 0, stream>>>(dstv, cnt);
    dinv_k<<<nb, 256, 0, stream>>>(cnt, dinv);
    scan1_k<<<nb, 256, 0, stream>>>(cnt, rowptr, bsum);
    scan2_k<<<1, 512, 0, stream>>>(bsum, nb);
    scan3_k<<<nb, 256, 0, stream>>>(rowptr, bsum);
    fill_k<<<eb, 256, 0, stream>>>(srcv, dstv, rowptr, fillc, colv);

    // Layer 0
    gemm_k<0><<<gb, 256, 0, stream>>>(x, W0, nullptr, nullptr, dinv, H0, 128, 128);
    agg_k<<<ab, 256, 0, stream>>>(H0, rowptr, colv, dinv, b0, H1);
    hipMemsetAsync(bnS, 0, 128 * 4 * 2, stream);
    bnstats_k<<<512, 256, 0, stream>>>(H1, bnS, bnQ);
    bnfinal_k<<<1, 128, 0, stream>>>(bnS, bnQ, g0, be0, bns, bnt);

    // Layer 1 (BN+ReLU fused into A-load)
    gemm_k<1><<<gb, 256, 0, stream>>>(H1, W1, bns, bnt, dinv, H0, 128, 128);
    agg_k<<<ab, 256, 0, stream>>>(H0, rowptr, colv, dinv, b1, H1);
    hipMemsetAsync(bnS, 0, 128 * 4 * 2, stream);
    bnstats_k<<<512, 256, 0, stream>>>(H1, bnS, bnQ);
    bnfinal_k<<<1, 128, 0, stream>>>(bnS, bnQ, g1, be1, bns, bnt);

    // Layer 2 (output 47 wide, stride 48) + fused log_softmax in aggregation
    gemm_k<1><<<gb, 256, 0, stream>>>(H1, W2, bns, bnt, dinv, H0, OUTD, OSTR);
    agg_out_k<<<ab, 256, 0, stream>>>(H0, rowptr, colv, dinv, b2, (float*)d_out);
}

// Round 2
// 643.736 us; speedup vs baseline: 1.4790x; 1.4790x over previous
//
#include <hip/hip_runtime.h>
#include <math.h>

#define N_NODES 100000
#define N_EDGES 1600000
#define HID 128
#define OUTD 47
#define OSTR 48

typedef short bf16x8 __attribute__((ext_vector_type(8)));
typedef float f32x4 __attribute__((ext_vector_type(4)));

__device__ inline unsigned short f2bf(float x) {
    union { float f; unsigned int u; } v; v.f = x;
    unsigned int r = v.u + 0x7fffu + ((v.u >> 16) & 1u);   // RNE
    return (unsigned short)(r >> 16);
}
__device__ inline float bf_lo(unsigned int u) { return __uint_as_float(u << 16); }
__device__ inline float bf_hi(unsigned int u) { return __uint_as_float(u & 0xffff0000u); }

// ---------------- CSR build ----------------

__global__ void count_k(const int* __restrict__ dst, int* __restrict__ cnt) {
    int e = blockIdx.x * 256 + threadIdx.x;
    if (e < N_EDGES) atomicAdd(&cnt[dst[e]], 1);
}

__global__ void dinv_k(const int* __restrict__ cnt, float* __restrict__ dinv) {
    int i = blockIdx.x * 256 + threadIdx.x;
    if (i < N_NODES) dinv[i] = rsqrtf((float)(cnt[i] + 1));  // +1 self-loop
}

__global__ void scan1_k(const int* __restrict__ cnt, int* __restrict__ rowptr,
                        int* __restrict__ bsum) {
    __shared__ int s[256];
    int t = threadIdx.x;
    int i = blockIdx.x * 256 + t;
    int v = (i < N_NODES) ? cnt[i] : 0;
    s[t] = v; __syncthreads();
    for (int off = 1; off < 256; off <<= 1) {
        int x = (t >= off) ? s[t - off] : 0;
        __syncthreads();
        s[t] += x;
        __syncthreads();
    }
    if (i < N_NODES) rowptr[i] = s[t] - v;   // exclusive
    if (t == 255) bsum[blockIdx.x] = s[t];   // block total
}

__global__ void scan2_k(int* __restrict__ bsum, int nb) {
    __shared__ int s[512];
    int t = threadIdx.x;
    int v = (t < nb) ? bsum[t] : 0;
    s[t] = v; __syncthreads();
    for (int off = 1; off < 512; off <<= 1) {
        int x = (t >= off) ? s[t - off] : 0;
        __syncthreads();
        s[t] += x;
        __syncthreads();
    }
    if (t < nb) bsum[t] = s[t] - v;          // exclusive block offsets
}

__global__ void scan3_k(int* __restrict__ rowptr, const int* __restrict__ bsum) {
    int i = blockIdx.x * 256 + threadIdx.x;
    if (i < N_NODES) rowptr[i] += bsum[blockIdx.x];
    if (i == 0) rowptr[N_NODES] = N_EDGES;
}

__global__ void fill_k(const int* __restrict__ src, const int* __restrict__ dst,
                       const int* __restrict__ rowptr, int* __restrict__ fillc,
                       int* __restrict__ colv) {
    int e = blockIdx.x * 256 + threadIdx.x;
    if (e < N_EDGES) {
        int d = dst[e];
        int p = atomicAdd(&fillc[d], 1);
        colv[rowptr[d] + p] = src[e];
    }
}

// ---------------- weight convert: W[k][n] fp32 -> Wt[n][k] bf16 ----------------

__global__ void convw_k(const float* __restrict__ W0, const float* __restrict__ W1,
                        const float* __restrict__ W2,
                        unsigned short* __restrict__ Wt0, unsigned short* __restrict__ Wt1,
                        unsigned short* __restrict__ Wt2) {
    int i = blockIdx.x * 256 + threadIdx.x;
    if (i < 16384) {
        int n = i >> 7, k = i & 127;
        Wt0[i] = f2bf(W0[k * 128 + n]);
        Wt1[i] = f2bf(W1[k * 128 + n]);
    }
    if (i < 48 * 128) {
        int n = i >> 7, k = i & 127;
        Wt2[i] = (n < OUTD) ? f2bf(W2[k * OUTD + n]) : (unsigned short)0;
    }
}

// ---------------- MFMA GEMM (M x 128 @ 128 x N), fused BN+ReLU, dinv prescale ----------------
// ABF16: A is bf16 (else fp32). MODE1: A' = relu(A*s+t). NT: N col tiles of 16.
// OBF16: store bf16 (else fp32).

template <int ABF16, int MODE, int NT, int OBF16>
__global__ __launch_bounds__(256) void gemm_k(
    const void* __restrict__ Ap, const unsigned short* __restrict__ Wt,
    const float* __restrict__ bns, const float* __restrict__ bnt,
    const float* __restrict__ dinv, void* __restrict__ Outp,
    int ncols, int ostride)
{
    __shared__ unsigned short WtL[NT * 16][136];
    __shared__ float sS[128], sT[128];

    int t = threadIdx.x;
    if (MODE) { if (t < 128) { sS[t] = bns[t]; sT[t] = bnt[t]; } }

    // stage Wt (bf16 [NT*16][128]) into padded LDS
    const int TOT = NT * 16 * 128;
    for (int e = t * 8; e < TOT; e += 256 * 8) {
        int n = e >> 7, k = e & 127;
        uint4 v = *(const uint4*)(Wt + e);
        *(uint4*)&WtL[n][k] = v;
    }
    __syncthreads();

    int wave = t >> 6, lane = t & 63;
    int quad = lane >> 4, m16 = lane & 15;
    int rbase = blockIdx.x * 128 + wave * 32;

    f32x4 acc[2][NT];
#pragma unroll
    for (int rt = 0; rt < 2; rt++)
#pragma unroll
        for (int ct = 0; ct < NT; ct++) acc[rt][ct] = (f32x4){0.f, 0.f, 0.f, 0.f};

#pragma unroll
    for (int kc = 0; kc < 4; kc++) {
        int kb = kc * 32 + quad * 8;
        bf16x8 afrag[2];
#pragma unroll
        for (int rt = 0; rt < 2; rt++) {
            int row = rbase + rt * 16 + m16;
            bool rv = (row < N_NODES);
            if (ABF16) {
                uint4 v = make_uint4(0, 0, 0, 0);
                if (rv) v = *(const uint4*)((const unsigned short*)Ap + (size_t)row * 128 + kb);
                if (MODE) {
                    unsigned int uu[4] = {v.x, v.y, v.z, v.w};
                    unsigned short* fp = (unsigned short*)&afrag[rt];
#pragma unroll
                    for (int i = 0; i < 4; i++) {
                        int k0 = kb + 2 * i;
                        float lo = fmaxf(bf_lo(uu[i]) * sS[k0] + sT[k0], 0.f);
                        float hi = fmaxf(bf_hi(uu[i]) * sS[k0 + 1] + sT[k0 + 1], 0.f);
                        fp[2 * i] = f2bf(lo);
                        fp[2 * i + 1] = f2bf(hi);
                    }
                } else {
                    afrag[rt] = *(bf16x8*)&v;
                }
            } else {
                const float* ap = (const float*)Ap + (size_t)row * 128 + kb;
                float4 f0 = make_float4(0.f, 0.f, 0.f, 0.f), f1 = f0;
                if (rv) { f0 = *(const float4*)ap; f1 = *(const float4*)(ap + 4); }
                unsigned short* fp = (unsigned short*)&afrag[rt];
                fp[0] = f2bf(f0.x); fp[1] = f2bf(f0.y); fp[2] = f2bf(f0.z); fp[3] = f2bf(f0.w);
                fp[4] = f2bf(f1.x); fp[5] = f2bf(f1.y); fp[6] = f2bf(f1.z); fp[7] = f2bf(f1.w);
            }
        }
#pragma unroll
        for (int ct = 0; ct < NT; ct++) {
            bf16x8 bfrag = *(bf16x8*)&WtL[ct * 16 + m16][kb];
#pragma unroll
            for (int rt = 0; rt < 2; rt++)
                acc[rt][ct] = __builtin_amdgcn_mfma_f32_16x16x32_bf16(
                    afrag[rt], bfrag, acc[rt][ct], 0, 0, 0);
        }
    }

#pragma unroll
    for (int rt = 0; rt < 2; rt++)
#pragma unroll
        for (int r = 0; r < 4; r++) {
            int row = rbase + rt * 16 + quad * 4 + r;
            if (row < N_NODES) {
                float d = dinv[row];
#pragma unroll
                for (int ct = 0; ct < NT; ct++) {
                    int c = ct * 16 + m16;
                    if (c < ncols) {
                        float val = acc[rt][ct][r] * d;
                        if (OBF16)
                            ((unsigned short*)Outp)[(size_t)row * ostride + c] = f2bf(val);
                        else
                            ((float*)Outp)[(size_t)row * ostride + c] = val;
                    }
                }
            }
        }
}

// ---------------- Aggregation: one wave per dst node, bf16 rows (uint/lane) ----------------

__global__ __launch_bounds__(256) void agg_k(
    const unsigned int* __restrict__ H, const int* __restrict__ rowptr,
    const int* __restrict__ colv, const float* __restrict__ dinv,
    const float* __restrict__ bias, unsigned int* __restrict__ out)
{
    int gw = (blockIdx.x * 256 + threadIdx.x) >> 6;
    int lane = threadIdx.x & 63;
    if (gw >= N_NODES) return;
    int rp = rowptr[gw], re = rowptr[gw + 1];
    unsigned int self = H[gw * 64 + lane];   // self-loop (prescaled row)
    float ax = bf_lo(self), ay = bf_hi(self);
    for (int j0 = rp; j0 < re; j0 += 64) {
        int idx = (j0 + lane < re) ? colv[j0 + lane] : 0;
        int n = min(64, re - j0);
        int j = 0;
        for (; j + 3 < n; j += 4) {
            int s0 = __shfl(idx, j), s1 = __shfl(idx, j + 1);
            int s2 = __shfl(idx, j + 2), s3 = __shfl(idx, j + 3);
            unsigned int u0 = H[s0 * 64 + lane], u1 = H[s1 * 64 + lane];
            unsigned int u2 = H[s2 * 64 + lane], u3 = H[s3 * 64 + lane];
            ax += bf_lo(u0) + bf_lo(u1) + bf_lo(u2) + bf_lo(u3);
            ay += bf_hi(u0) + bf_hi(u1) + bf_hi(u2) + bf_hi(u3);
        }
        for (; j < n; j++) {
            int s = __shfl(idx, j);
            unsigned int u = H[s * 64 + lane];
            ax += bf_lo(u);
            ay += bf_hi(u);
        }
    }
    float d = dinv[gw];
    float2 b = ((const float2*)bias)[lane];
    unsigned short rx = f2bf(ax * d + b.x);
    unsigned short ry = f2bf(ay * d + b.y);
    out[gw * 64 + lane] = (unsigned int)rx | ((unsigned int)ry << 16);
}

// ---------------- Final aggregation (47-wide fp32) + bias + log_softmax ----------------

__global__ __launch_bounds__(256) void agg_out_k(
    const float* __restrict__ Hp, const int* __restrict__ rowptr,
    const int* __restrict__ colv, const float* __restrict__ dinv,
    const float* __restrict__ b2, float* __restrict__ out)
{
    int gw = (blockIdx.x * 256 + threadIdx.x) >> 6;
    int lane = threadIdx.x & 63;
    if (gw >= N_NODES) return;
    bool act = lane < OUTD;
    int rp = rowptr[gw], re = rowptr[gw + 1];
    float acc = act ? Hp[gw * OSTR + lane] : 0.f;
    for (int j0 = rp; j0 < re; j0 += 64) {
        int idx = (j0 + lane < re) ? colv[j0 + lane] : 0;
        int n = min(64, re - j0);
        int j = 0;
        for (; j + 3 < n; j += 4) {
            int s0 = __shfl(idx, j), s1 = __shfl(idx, j + 1);
            int s2 = __shfl(idx, j + 2), s3 = __shfl(idx, j + 3);
            if (act)
                acc += Hp[s0 * OSTR + lane] + Hp[s1 * OSTR + lane]
                     + Hp[s2 * OSTR + lane] + Hp[s3 * OSTR + lane];
        }
        for (; j < n; j++) {
            int s = __shfl(idx, j);
            if (act) acc += Hp[s * OSTR + lane];
        }
    }
    float v = acc * dinv[gw] + (act ? b2[lane] : 0.f);
    float m = act ? v : -INFINITY;
    for (int off = 32; off; off >>= 1) m = fmaxf(m, __shfl_xor(m, off));
    float ex = act ? expf(v - m) : 0.f;
    float sum = ex;
    for (int off = 32; off; off >>= 1) sum += __shfl_xor(sum, off);
    if (act) out[(size_t)gw * OUTD + lane] = v - m - logf(sum);
}

// ---------------- BatchNorm stats (bf16 input) ----------------

__global__ __launch_bounds__(256) void bnstats_k(const unsigned int* __restrict__ H,
                                                 float* __restrict__ sum,
                                                 float* __restrict__ sq)
{
    __shared__ float2 ls[256], lq[256];
    int t = threadIdx.x;
    int idx = blockIdx.x * 256 + t;
    int stride = gridDim.x * 256;            // multiple of 64 -> channel pair = t & 63
    float sx = 0.f, sy = 0.f, qx = 0.f, qy = 0.f;
    for (; idx < N_NODES * 64; idx += stride) {
        unsigned int u = H[idx];
        float x = bf_lo(u), y = bf_hi(u);
        sx += x; sy += y; qx += x * x; qy += y * y;
    }
    ls[t] = make_float2(sx, sy);
    lq[t] = make_float2(qx, qy);
    __syncthreads();
    if (t < 64) {
        float2 a = ls[t], b = ls[t + 64], c = ls[t + 128], d = ls[t + 192];
        float2 e = lq[t], f = lq[t + 64], g = lq[t + 128], h = lq[t + 192];
        int c0 = t * 2;
        atomicAdd(&sum[c0],     a.x + b.x + c.x + d.x);
        atomicAdd(&sum[c0 + 1], a.y + b.y + c.y + d.y);
        atomicAdd(&sq[c0],      e.x + f.x + g.x + h.x);
        atomicAdd(&sq[c0 + 1],  e.y + f.y + g.y + h.y);
    }
}

__global__ void bnfinal_k(const float* __restrict__ sum, const float* __restrict__ sq,
                          const float* __restrict__ g, const float* __restrict__ be,
                          float* __restrict__ bs, float* __restrict__ bt)
{
    int c = threadIdx.x;
    if (c < 128) {
        float mean = sum[c] * (1.0f / N_NODES);
        float var = sq[c] * (1.0f / N_NODES) - mean * mean;
        float inv = rsqrtf(var + 1e-5f);
        float s = g[c] * inv;
        bs[c] = s;
        bt[c] = be[c] - mean * s;
    }
}

// ---------------- launch ----------------

extern "C" void kernel_launch(void* const* d_in, const int* in_sizes, int n_in,
                              void* d_out, int out_size, void* d_ws, size_t ws_size,
                              hipStream_t stream)
{
    const float* x   = (const float*)d_in[0];
    const int*   ei  = (const int*)d_in[1];
    const float* W0  = (const float*)d_in[2];
    const float* b0  = (const float*)d_in[3];
    const float* W1  = (const float*)d_in[4];
    const float* b1  = (const float*)d_in[5];
    const float* W2  = (const float*)d_in[6];
    const float* b2  = (const float*)d_in[7];
    const float* g0  = (const float*)d_in[8];
    const float* be0 = (const float*)d_in[9];
    const float* g1  = (const float*)d_in[10];
    const float* be1 = (const float*)d_in[11];
    const int* srcv = ei;
    const int* dstv = ei + N_EDGES;

    char* w = (char*)d_ws;
    unsigned int* H0 = (unsigned int*)w;  w += (size_t)N_NODES * 128 * 2;   // bf16 [N][128]
    unsigned int* H1 = (unsigned int*)w;  w += (size_t)N_NODES * 128 * 2;   // bf16 [N][128]
    float* Hf = (float*)w;                w += (size_t)N_NODES * OSTR * 4;  // fp32 [N][48]
    unsigned short* Wt0 = (unsigned short*)w; w += 16384 * 2;
    unsigned short* Wt1 = (unsigned short*)w; w += 16384 * 2;
    unsigned short* Wt2 = (unsigned short*)w; w += 48 * 128 * 2;
    int* cnt  = (int*)w;        w += (size_t)N_NODES * 4;
    int* fillc = (int*)w;       w += (size_t)N_NODES * 4;
    int* rowptr = (int*)w;      w += (size_t)(N_NODES + 4) * 4;
    int* colv = (int*)w;        w += (size_t)N_EDGES * 4;
    float* dinv = (float*)w;    w += (size_t)N_NODES * 4;
    int* bsum = (int*)w;        w += 512 * 4;
    float* bnS = (float*)w;     w += 128 * 4;
    float* bnQ = (float*)w;     w += 128 * 4;
    float* bns = (float*)w;     w += 128 * 4;
    float* bnt = (float*)w;     w += 128 * 4;

    int eb = (N_EDGES + 255) / 256;       // 6250
    int nb = (N_NODES + 255) / 256;       // 391
    int gb = (N_NODES + 127) / 128;       // 782
    int ab = (N_NODES * 64 + 255) / 256;  // 25000

    hipMemsetAsync(cnt, 0, (size_t)N_NODES * 4 * 2, stream);  // cnt + fillc (contiguous)

    count_k<<<eb, 256, 0, stream>>>(dstv, cnt);
    convw_k<<<64, 256, 0, stream>>>(W0, W1, W2, Wt0, Wt1, Wt2);
    dinv_k<<<nb, 256, 0, stream>>>(cnt, dinv);
    scan1_k<<<nb, 256, 0, stream>>>(cnt, rowptr, bsum);
    scan2_k<<<1, 512, 0, stream>>>(bsum, nb);
    scan3_k<<<nb, 256, 0, stream>>>(rowptr, bsum);
    fill_k<<<eb, 256, 0, stream>>>(srcv, dstv, rowptr, fillc, colv);

    // Layer 0: x fp32 -> H0 bf16 (dinv-prescaled)
    gemm_k<0, 0, 8, 1><<<gb, 256, 0, stream>>>(x, Wt0, nullptr, nullptr, dinv, H0, 128, 128);
    agg_k<<<ab, 256, 0, stream>>>(H0, rowptr, colv, dinv, b0, H1);
    hipMemsetAsync(bnS, 0, 128 * 4 * 2, stream);
    bnstats_k<<<512, 256, 0, stream>>>(H1, bnS, bnQ);
    bnfinal_k<<<1, 128, 0, stream>>>(bnS, bnQ, g0, be0, bns, bnt);

    // Layer 1: BN+ReLU fused into A-load, bf16 MFMA
    gemm_k<1, 1, 8, 1><<<gb, 256, 0, stream>>>(H1, Wt1, bns, bnt, dinv, H0, 128, 128);
    agg_k<<<ab, 256, 0, stream>>>(H0, rowptr, colv, dinv, b1, H1);
    hipMemsetAsync(bnS, 0, 128 * 4 * 2, stream);
    bnstats_k<<<512, 256, 0, stream>>>(H1, bnS, bnQ);
    bnfinal_k<<<1, 128, 0, stream>>>(bnS, bnQ, g1, be1, bns, bnt);

    // Layer 2: 47-wide out (fp32, stride 48) + fused log_softmax aggregation
    gemm_k<1, 1, 3, 0><<<gb, 256, 0, stream>>>(H1, Wt2, bns, bnt, dinv, Hf, OUTD, OSTR);
    agg_out_k<<<ab, 256, 0, stream>>>(Hf, rowptr, colv, dinv, b2, (float*)d_out);
}

// Round 3
// 549.597 us; speedup vs baseline: 1.7324x; 1.1713x over previous
//
#include <hip/hip_runtime.h>
#include <math.h>

#define N_NODES 100000
#define N_EDGES 1600000
#define HID 128
#define OUTD 47
#define OSTR 48

#define NPB 128                       // nodes per bucket
#define NB 782                        // ceil(100000/128)
#define BCAP 4096                     // record capacity per bucket (mean 2046, sigma ~45)
#define CHUNK 8192                    // edges per phase-A block

typedef short bf16x8 __attribute__((ext_vector_type(8)));
typedef float f32x4 __attribute__((ext_vector_type(4)));

__device__ inline unsigned short f2bf(float x) {
    union { float f; unsigned int u; } v; v.f = x;
    unsigned int r = v.u + 0x7fffu + ((v.u >> 16) & 1u);   // RNE
    return (unsigned short)(r >> 16);
}
__device__ inline float bf_lo(unsigned int u) { return __uint_as_float(u << 16); }
__device__ inline float bf_hi(unsigned int u) { return __uint_as_float(u & 0xffff0000u); }

// ---------------- Phase A: bin edges by dst bucket (LDS counting sort per chunk) ----------------

__global__ __launch_bounds__(256) void binA_k(
    const int* __restrict__ src, const int* __restrict__ dst,
    int* __restrict__ gcur, unsigned int* __restrict__ binned)
{
    __shared__ unsigned int sortedL[CHUNK];   // 32 KB
    __shared__ int cntL[NB];
    __shared__ int excL[NB];
    __shared__ int curL[NB];
    __shared__ int gposL[NB];
    __shared__ int partial[256];

    int t = threadIdx.x;
    int e0 = blockIdx.x * CHUNK;

    for (int i = t; i < NB; i += 256) cntL[i] = 0;
    __syncthreads();

    for (int i = t; i < CHUNK; i += 256) {
        int e = e0 + i;
        if (e < N_EDGES) atomicAdd(&cntL[dst[e] >> 7], 1);
    }
    __syncthreads();

    // exclusive scan of cntL[NB]: 4 elements/thread + block scan of partials
    int b4 = t * 4;
    int c0 = (b4 + 0 < NB) ? cntL[b4 + 0] : 0;
    int c1 = (b4 + 1 < NB) ? cntL[b4 + 1] : 0;
    int c2 = (b4 + 2 < NB) ? cntL[b4 + 2] : 0;
    int c3 = (b4 + 3 < NB) ? cntL[b4 + 3] : 0;
    int lsum = c0 + c1 + c2 + c3;
    partial[t] = lsum;
    __syncthreads();
    for (int off = 1; off < 256; off <<= 1) {
        int x = (t >= off) ? partial[t - off] : 0;
        __syncthreads();
        partial[t] += x;
        __syncthreads();
    }
    int pbase = partial[t] - lsum;
    if (b4 + 0 < NB) { excL[b4 + 0] = pbase;                curL[b4 + 0] = pbase; }
    if (b4 + 1 < NB) { excL[b4 + 1] = pbase + c0;           curL[b4 + 1] = pbase + c0; }
    if (b4 + 2 < NB) { excL[b4 + 2] = pbase + c0 + c1;      curL[b4 + 2] = pbase + c0 + c1; }
    if (b4 + 3 < NB) { excL[b4 + 3] = pbase + c0 + c1 + c2; curL[b4 + 3] = pbase + c0 + c1 + c2; }
    __syncthreads();

    // scatter packed records into LDS sorted-by-bucket
    for (int i = t; i < CHUNK; i += 256) {
        int e = e0 + i;
        if (e < N_EDGES) {
            int d = dst[e];
            int s = src[e];
            int pos = atomicAdd(&curL[d >> 7], 1);
            sortedL[pos] = ((unsigned int)s << 7) | (unsigned int)(d & 127);
        }
    }
    __syncthreads();

    // claim global space per bucket (one atomic per non-empty bucket per block)
    for (int b = t; b < NB; b += 256) {
        int c = cntL[b];
        gposL[b] = c ? atomicAdd(&gcur[b], c) : 0;
    }
    __syncthreads();

    // copy runs out, one wave per bucket (contiguous writes)
    int wv = t >> 6, ln = t & 63;
    for (int b = wv; b < NB; b += 4) {
        int c = cntL[b];
        int off = excL[b];
        unsigned int* dp = binned + (size_t)b * BCAP + gposL[b];
        for (int j = ln; j < c; j += 64) dp[j] = sortedL[off + j];
    }
}

// ---------------- scan bucket counts -> bucket base offsets ----------------

__global__ void scanB_k(const int* __restrict__ gcur, int* __restrict__ bbase,
                        int* __restrict__ rowptr) {
    __shared__ int s[1024];
    int t = threadIdx.x;
    int v = (t < NB) ? gcur[t] : 0;
    s[t] = v; __syncthreads();
    for (int off = 1; off < 1024; off <<= 1) {
        int x = (t >= off) ? s[t - off] : 0;
        __syncthreads();
        s[t] += x;
        __syncthreads();
    }
    if (t < NB) bbase[t] = s[t] - v;
    if (t == 0) { bbase[NB] = N_EDGES; rowptr[N_NODES] = N_EDGES; }
}

// ---------------- Phase B: per-bucket CSR finalize (rowptr, dinv, colv) ----------------

__global__ __launch_bounds__(256) void binB_k(
    const unsigned int* __restrict__ binned, const int* __restrict__ gcur,
    const int* __restrict__ bbase, int* __restrict__ rowptr,
    float* __restrict__ dinv, int* __restrict__ colv)
{
    __shared__ unsigned int recL[BCAP];   // 16 KB
    __shared__ int colL[BCAP];            // 16 KB
    __shared__ int lcnt[NPB];
    __shared__ int lcur[NPB];
    __shared__ int sc[256];

    int b = blockIdx.x, t = threadIdx.x;
    int cnt = gcur[b];
    int base = bbase[b];
    const unsigned int* rp = binned + (size_t)b * BCAP;

    if (t < NPB) lcnt[t] = 0;
    __syncthreads();
    for (int i = t; i < cnt; i += 256) {
        unsigned int r = rp[i];
        recL[i] = r;
        atomicAdd(&lcnt[r & 127], 1);
    }
    __syncthreads();

    int v = (t < NPB) ? lcnt[t] : 0;
    sc[t] = v; __syncthreads();
    for (int off = 1; off < 256; off <<= 1) {
        int x = (t >= off) ? sc[t - off] : 0;
        __syncthreads();
        sc[t] += x;
        __syncthreads();
    }
    int node = b * NPB + t;
    if (t < NPB) {
        lcur[t] = sc[t] - v;
        if (node < N_NODES) {
            rowptr[node] = base + sc[t] - v;
            dinv[node] = rsqrtf((float)(v + 1));    // +1 self-loop
        }
    }
    __syncthreads();

    for (int i = t; i < cnt; i += 256) {
        unsigned int r = recL[i];
        int pos = atomicAdd(&lcur[r & 127], 1);
        colL[pos] = (int)(r >> 7);
    }
    __syncthreads();
    for (int i = t; i < cnt; i += 256) colv[base + i] = colL[i];
}

// ---------------- weight convert: W[k][n] fp32 -> Wt[n][k] bf16 ----------------

__global__ void convw_k(const float* __restrict__ W0, const float* __restrict__ W1,
                        const float* __restrict__ W2,
                        unsigned short* __restrict__ Wt0, unsigned short* __restrict__ Wt1,
                        unsigned short* __restrict__ Wt2) {
    int i = blockIdx.x * 256 + threadIdx.x;
    if (i < 16384) {
        int n = i >> 7, k = i & 127;
        Wt0[i] = f2bf(W0[k * 128 + n]);
        Wt1[i] = f2bf(W1[k * 128 + n]);
    }
    if (i < 48 * 128) {
        int n = i >> 7, k = i & 127;
        Wt2[i] = (n < OUTD) ? f2bf(W2[k * OUTD + n]) : (unsigned short)0;
    }
}

// ---------------- MFMA GEMM (M x 128 @ 128 x N), fused BN+ReLU, dinv prescale ----------------

template <int ABF16, int MODE, int NT, int OBF16>
__global__ __launch_bounds__(256) void gemm_k(
    const void* __restrict__ Ap, const unsigned short* __restrict__ Wt,
    const float* __restrict__ bns, const float* __restrict__ bnt,
    const float* __restrict__ dinv, void* __restrict__ Outp,
    int ncols, int ostride)
{
    __shared__ unsigned short WtL[NT * 16][136];
    __shared__ float sS[128], sT[128];

    int t = threadIdx.x;
    if (MODE) { if (t < 128) { sS[t] = bns[t]; sT[t] = bnt[t]; } }

    const int TOT = NT * 16 * 128;
    for (int e = t * 8; e < TOT; e += 256 * 8) {
        int n = e >> 7, k = e & 127;
        uint4 v = *(const uint4*)(Wt + e);
        *(uint4*)&WtL[n][k] = v;
    }
    __syncthreads();

    int wave = t >> 6, lane = t & 63;
    int quad = lane >> 4, m16 = lane & 15;
    int rbase = blockIdx.x * 128 + wave * 32;

    f32x4 acc[2][NT];
#pragma unroll
    for (int rt = 0; rt < 2; rt++)
#pragma unroll
        for (int ct = 0; ct < NT; ct++) acc[rt][ct] = (f32x4){0.f, 0.f, 0.f, 0.f};

#pragma unroll
    for (int kc = 0; kc < 4; kc++) {
        int kb = kc * 32 + quad * 8;
        bf16x8 afrag[2];
#pragma unroll
        for (int rt = 0; rt < 2; rt++) {
            int row = rbase + rt * 16 + m16;
            bool rv = (row < N_NODES);
            if (ABF16) {
                uint4 v = make_uint4(0, 0, 0, 0);
                if (rv) v = *(const uint4*)((const unsigned short*)Ap + (size_t)row * 128 + kb);
                if (MODE) {
                    unsigned int uu[4] = {v.x, v.y, v.z, v.w};
                    unsigned short* fp = (unsigned short*)&afrag[rt];
#pragma unroll
                    for (int i = 0; i < 4; i++) {
                        int k0 = kb + 2 * i;
                        float lo = fmaxf(bf_lo(uu[i]) * sS[k0] + sT[k0], 0.f);
                        float hi = fmaxf(bf_hi(uu[i]) * sS[k0 + 1] + sT[k0 + 1], 0.f);
                        fp[2 * i] = f2bf(lo);
                        fp[2 * i + 1] = f2bf(hi);
                    }
                } else {
                    afrag[rt] = *(bf16x8*)&v;
                }
            } else {
                const float* ap = (const float*)Ap + (size_t)row * 128 + kb;
                float4 f0 = make_float4(0.f, 0.f, 0.f, 0.f), f1 = f0;
                if (rv) { f0 = *(const float4*)ap; f1 = *(const float4*)(ap + 4); }
                unsigned short* fp = (unsigned short*)&afrag[rt];
                fp[0] = f2bf(f0.x); fp[1] = f2bf(f0.y); fp[2] = f2bf(f0.z); fp[3] = f2bf(f0.w);
                fp[4] = f2bf(f1.x); fp[5] = f2bf(f1.y); fp[6] = f2bf(f1.z); fp[7] = f2bf(f1.w);
            }
        }
#pragma unroll
        for (int ct = 0; ct < NT; ct++) {
            bf16x8 bfrag = *(bf16x8*)&WtL[ct * 16 + m16][kb];
#pragma unroll
            for (int rt = 0; rt < 2; rt++)
                acc[rt][ct] = __builtin_amdgcn_mfma_f32_16x16x32_bf16(
                    afrag[rt], bfrag, acc[rt][ct], 0, 0, 0);
        }
    }

#pragma unroll
    for (int rt = 0; rt < 2; rt++)
#pragma unroll
        for (int r = 0; r < 4; r++) {
            int row = rbase + rt * 16 + quad * 4 + r;
            if (row < N_NODES) {
                float d = dinv[row];
#pragma unroll
                for (int ct = 0; ct < NT; ct++) {
                    int c = ct * 16 + m16;
                    if (c < ncols) {
                        float val = acc[rt][ct][r] * d;
                        if (OBF16)
                            ((unsigned short*)Outp)[(size_t)row * ostride + c] = f2bf(val);
                        else
                            ((float*)Outp)[(size_t)row * ostride + c] = val;
                    }
                }
            }
        }
}

// ---------------- Aggregation: one wave per dst node, bf16 rows (uint/lane) ----------------

__global__ __launch_bounds__(256) void agg_k(
    const unsigned int* __restrict__ H, const int* __restrict__ rowptr,
    const int* __restrict__ colv, const float* __restrict__ dinv,
    const float* __restrict__ bias, unsigned int* __restrict__ out)
{
    int gw = (blockIdx.x * 256 + threadIdx.x) >> 6;
    int lane = threadIdx.x & 63;
    if (gw >= N_NODES) return;
    int rp = rowptr[gw], re = rowptr[gw + 1];
    unsigned int self = H[gw * 64 + lane];   // self-loop (prescaled row)
    float ax = bf_lo(self), ay = bf_hi(self);
    for (int j0 = rp; j0 < re; j0 += 64) {
        int idx = (j0 + lane < re) ? colv[j0 + lane] : 0;
        int n = min(64, re - j0);
        int j = 0;
        for (; j + 3 < n; j += 4) {
            int s0 = __shfl(idx, j), s1 = __shfl(idx, j + 1);
            int s2 = __shfl(idx, j + 2), s3 = __shfl(idx, j + 3);
            unsigned int u0 = H[s0 * 64 + lane], u1 = H[s1 * 64 + lane];
            unsigned int u2 = H[s2 * 64 + lane], u3 = H[s3 * 64 + lane];
            ax += bf_lo(u0) + bf_lo(u1) + bf_lo(u2) + bf_lo(u3);
            ay += bf_hi(u0) + bf_hi(u1) + bf_hi(u2) + bf_hi(u3);
        }
        for (; j < n; j++) {
            int s = __shfl(idx, j);
            unsigned int u = H[s * 64 + lane];
            ax += bf_lo(u);
            ay += bf_hi(u);
        }
    }
    float d = dinv[gw];
    float2 b = ((const float2*)bias)[lane];
    unsigned short rx = f2bf(ax * d + b.x);
    unsigned short ry = f2bf(ay * d + b.y);
    out[gw * 64 + lane] = (unsigned int)rx | ((unsigned int)ry << 16);
}

// ---------------- Final aggregation (47-wide fp32) + bias + log_softmax ----------------

__global__ __launch_bounds__(256) void agg_out_k(
    const float* __restrict__ Hp, const int* __restrict__ rowptr,
    const int* __restrict__ colv, const float* __restrict__ dinv,
    const float* __restrict__ b2, float* __restrict__ out)
{
    int gw = (blockIdx.x * 256 + threadIdx.x) >> 6;
    int lane = threadIdx.x & 63;
    if (gw >= N_NODES) return;
    bool act = lane < OUTD;
    int rp = rowptr[gw], re = rowptr[gw + 1];
    float acc = act ? Hp[gw * OSTR + lane] : 0.f;
    for (int j0 = rp; j0 < re; j0 += 64) {
        int idx = (j0 + lane < re) ? colv[j0 + lane] : 0;
        int n = min(64, re - j0);
        int j = 0;
        for (; j + 3 < n; j += 4) {
            int s0 = __shfl(idx, j), s1 = __shfl(idx, j + 1);
            int s2 = __shfl(idx, j + 2), s3 = __shfl(idx, j + 3);
            if (act)
                acc += Hp[s0 * OSTR + lane] + Hp[s1 * OSTR + lane]
                     + Hp[s2 * OSTR + lane] + Hp[s3 * OSTR + lane];
        }
        for (; j < n; j++) {
            int s = __shfl(idx, j);
            if (act) acc += Hp[s * OSTR + lane];
        }
    }
    float v = acc * dinv[gw] + (act ? b2[lane] : 0.f);
    float m = act ? v : -INFINITY;
    for (int off = 32; off; off >>= 1) m = fmaxf(m, __shfl_xor(m, off));
    float ex = act ? expf(v - m) : 0.f;
    float sum = ex;
    for (int off = 32; off; off >>= 1) sum += __shfl_xor(sum, off);
    if (act) out[(size_t)gw * OUTD + lane] = v - m - logf(sum);
}

// ---------------- BatchNorm stats (bf16 input) ----------------

__global__ __launch_bounds__(256) void bnstats_k(const unsigned int* __restrict__ H,
                                                 float* __restrict__ sum,
                                                 float* __restrict__ sq)
{
    __shared__ float2 ls[256], lq[256];
    int t = threadIdx.x;
    int idx = blockIdx.x * 256 + t;
    int stride = gridDim.x * 256;
    float sx = 0.f, sy = 0.f, qx = 0.f, qy = 0.f;
    for (; idx < N_NODES * 64; idx += stride) {
        unsigned int u = H[idx];
        float x = bf_lo(u), y = bf_hi(u);
        sx += x; sy += y; qx += x * x; qy += y * y;
    }
    ls[t] = make_float2(sx, sy);
    lq[t] = make_float2(qx, qy);
    __syncthreads();
    if (t < 64) {
        float2 a = ls[t], b = ls[t + 64], c = ls[t + 128], d = ls[t + 192];
        float2 e = lq[t], f = lq[t + 64], g = lq[t + 128], h = lq[t + 192];
        int c0 = t * 2;
        atomicAdd(&sum[c0],     a.x + b.x + c.x + d.x);
        atomicAdd(&sum[c0 + 1], a.y + b.y + c.y + d.y);
        atomicAdd(&sq[c0],      e.x + f.x + g.x + h.x);
        atomicAdd(&sq[c0 + 1],  e.y + f.y + g.y + h.y);
    }
}

__global__ void bnfinal_k(const float* __restrict__ sum, const float* __restrict__ sq,
                          const float* __restrict__ g, const float* __restrict__ be,
                          float* __restrict__ bs, float* __restrict__ bt)
{
    int c = threadIdx.x;
    if (c < 128) {
        float mean = sum[c] * (1.0f / N_NODES);
        float var = sq[c] * (1.0f / N_NODES) - mean * mean;
        float inv = rsqrtf(var + 1e-5f);
        float s = g[c] * inv;
        bs[c] = s;
        bt[c] = be[c] - mean * s;
    }
}

// ---------------- launch ----------------

extern "C" void kernel_launch(void* const* d_in, const int* in_sizes, int n_in,
                              void* d_out, int out_size, void* d_ws, size_t ws_size,
                              hipStream_t stream)
{
    const float* x   = (const float*)d_in[0];
    const int*   ei  = (const int*)d_in[1];
    const float* W0  = (const float*)d_in[2];
    const float* b0  = (const float*)d_in[3];
    const float* W1  = (const float*)d_in[4];
    const float* b1  = (const float*)d_in[5];
    const float* W2  = (const float*)d_in[6];
    const float* b2  = (const float*)d_in[7];
    const float* g0  = (const float*)d_in[8];
    const float* be0 = (const float*)d_in[9];
    const float* g1  = (const float*)d_in[10];
    const float* be1 = (const float*)d_in[11];
    const int* srcv = ei;
    const int* dstv = ei + N_EDGES;

    char* w = (char*)d_ws;
    unsigned int* H0 = (unsigned int*)w;  w += (size_t)N_NODES * 128 * 2;   // bf16 [N][128]
    unsigned int* H1 = (unsigned int*)w;  w += (size_t)N_NODES * 128 * 2;   // bf16 [N][128]
    float* Hf = (float*)w;                w += (size_t)N_NODES * OSTR * 4;  // fp32 [N][48]
    unsigned int* binned = (unsigned int*)w; w += (size_t)NB * BCAP * 4;    // 12.8 MB
    unsigned short* Wt0 = (unsigned short*)w; w += 16384 * 2;
    unsigned short* Wt1 = (unsigned short*)w; w += 16384 * 2;
    unsigned short* Wt2 = (unsigned short*)w; w += 48 * 128 * 2;
    int* gcur = (int*)w;        w += (size_t)(NB + 2) * 4;
    int* bbase = (int*)w;       w += (size_t)(NB + 2) * 4;
    int* rowptr = (int*)w;      w += (size_t)(N_NODES + 4) * 4;
    int* colv = (int*)w;        w += (size_t)N_EDGES * 4;
    float* dinv = (float*)w;    w += (size_t)N_NODES * 4;
    float* bnS = (float*)w;     w += 128 * 4;
    float* bnQ = (float*)w;     w += 128 * 4;
    float* bns = (float*)w;     w += 128 * 4;
    float* bnt = (float*)w;     w += 128 * 4;

    int gb = (N_NODES + 127) / 128;       // 782
    int ab = (N_NODES * 64 + 255) / 256;  // 25000
    int nchA = (N_EDGES + CHUNK - 1) / CHUNK;  // 196

    hipMemsetAsync(gcur, 0, (size_t)NB * 4, stream);

    convw_k<<<64, 256, 0, stream>>>(W0, W1, W2, Wt0, Wt1, Wt2);
    binA_k<<<nchA, 256, 0, stream>>>(srcv, dstv, gcur, binned);
    scanB_k<<<1, 1024, 0, stream>>>(gcur, bbase, rowptr);
    binB_k<<<NB, 256, 0, stream>>>(binned, gcur, bbase, rowptr, dinv, colv);

    // Layer 0: x fp32 -> H0 bf16 (dinv-prescaled)
    gemm_k<0, 0, 8, 1><<<gb, 256, 0, stream>>>(x, Wt0, nullptr, nullptr, dinv, H0, 128, 128);
    agg_k<<<ab, 256, 0, stream>>>(H0, rowptr, colv, dinv, b0, H1);
    hipMemsetAsync(bnS, 0, 128 * 4 * 2, stream);
    bnstats_k<<<512, 256, 0, stream>>>(H1, bnS, bnQ);
    bnfinal_k<<<1, 128, 0, stream>>>(bnS, bnQ, g0, be0, bns, bnt);

    // Layer 1: BN+ReLU fused into A-load, bf16 MFMA
    gemm_k<1, 1, 8, 1><<<gb, 256, 0, stream>>>(H1, Wt1, bns, bnt, dinv, H0, 128, 128);
    agg_k<<<ab, 256, 0, stream>>>(H0, rowptr, colv, dinv, b1, H1);
    hipMemsetAsync(bnS, 0, 128 * 4 * 2, stream);
    bnstats_k<<<512, 256, 0, stream>>>(H1, bnS, bnQ);
    bnfinal_k<<<1, 128, 0, stream>>>(bnS, bnQ, g1, be1, bns, bnt);

    // Layer 2: 47-wide out (fp32, stride 48) + fused log_softmax aggregation
    gemm_k<1, 1, 3, 0><<<gb, 256, 0, stream>>>(H1, Wt2, bns, bnt, dinv, Hf, OUTD, OSTR);
    agg_out_k<<<ab, 256, 0, stream>>>(Hf, rowptr, colv, dinv, b2, (float*)d_out);
}

// Round 4
// 519.632 us; speedup vs baseline: 1.8323x; 1.0577x over previous
//
#include <hip/hip_runtime.h>
#include <math.h>

#define N_NODES 100000
#define N_EDGES 1600000
#define HID 128
#define OUTD 47
#define OSTR 48

#define NPB 128                       // nodes per fine bucket
#define NB 782                        // ceil(100000/128)
#define BCAP 2560                     // record capacity per fine bucket (mean 2046, sigma ~45)
#define CHUNK 2048                    // edges per phase-A block
#define NCHB 782                      // phase-A blocks

typedef short bf16x8 __attribute__((ext_vector_type(8)));
typedef float f32x4 __attribute__((ext_vector_type(4)));

__device__ inline unsigned short f2bf(float x) {
    union { float f; unsigned int u; } v; v.f = x;
    unsigned int r = v.u + 0x7fffu + ((v.u >> 16) & 1u);   // RNE
    return (unsigned short)(r >> 16);
}
__device__ inline float bf_lo(unsigned int u) { return __uint_as_float(u << 16); }
__device__ inline float bf_hi(unsigned int u) { return __uint_as_float(u & 0xffff0000u); }

// src-chunk for gather locality: 16 chunks of 6250 nodes (1.6 MB of bf16 H each)
__device__ inline unsigned int src_chunk(unsigned int s) {
    return (s * 42950u) >> 28;   // == s / 6250 for s < 100000
}

// ---------------- Phase A: bin edges by dst fine-bucket (LDS counting sort per 2048-chunk) ----------------

__global__ __launch_bounds__(256) void binA_k(
    const int* __restrict__ src, const int* __restrict__ dst,
    int* __restrict__ gcur, unsigned int* __restrict__ binned)
{
    __shared__ unsigned int sortedL[CHUNK];       // 8 KB
    __shared__ unsigned short bucketOf[CHUNK];    // 4 KB
    __shared__ int cntL[NB];                      // 3.1 KB
    __shared__ int excL[NB];
    __shared__ int curL[NB];
    __shared__ int gposL[NB];
    __shared__ int partial[256];

    int t = threadIdx.x;
    int e0 = blockIdx.x * CHUNK;

    for (int i = t; i < NB; i += 256) cntL[i] = 0;
    __syncthreads();

    // histogram (8 edges/thread)
    for (int i = t; i < CHUNK; i += 256) {
        int e = e0 + i;
        if (e < N_EDGES) atomicAdd(&cntL[dst[e] >> 7], 1);
    }
    __syncthreads();

    // exclusive scan of cntL[NB]: 4 elements/thread + block scan of partials
    int b4 = t * 4;
    int c0 = (b4 + 0 < NB) ? cntL[b4 + 0] : 0;
    int c1 = (b4 + 1 < NB) ? cntL[b4 + 1] : 0;
    int c2 = (b4 + 2 < NB) ? cntL[b4 + 2] : 0;
    int c3 = (b4 + 3 < NB) ? cntL[b4 + 3] : 0;
    int lsum = c0 + c1 + c2 + c3;
    partial[t] = lsum;
    __syncthreads();
    for (int off = 1; off < 256; off <<= 1) {
        int x = (t >= off) ? partial[t - off] : 0;
        __syncthreads();
        partial[t] += x;
        __syncthreads();
    }
    int pbase = partial[t] - lsum;
    if (b4 + 0 < NB) { excL[b4 + 0] = pbase;                curL[b4 + 0] = pbase; }
    if (b4 + 1 < NB) { excL[b4 + 1] = pbase + c0;           curL[b4 + 1] = pbase + c0; }
    if (b4 + 2 < NB) { excL[b4 + 2] = pbase + c0 + c1;      curL[b4 + 2] = pbase + c0 + c1; }
    if (b4 + 3 < NB) { excL[b4 + 3] = pbase + c0 + c1 + c2; curL[b4 + 3] = pbase + c0 + c1 + c2; }
    __syncthreads();

    int tot = partial[255];   // valid records in this chunk

    // scatter packed records into LDS sorted-by-bucket, remember bucket per position
    for (int i = t; i < CHUNK; i += 256) {
        int e = e0 + i;
        if (e < N_EDGES) {
            int d = dst[e];
            int s = src[e];
            int bkt = d >> 7;
            int pos = atomicAdd(&curL[bkt], 1);
            sortedL[pos] = ((unsigned int)s << 7) | (unsigned int)(d & 127);
            bucketOf[pos] = (unsigned short)bkt;
        }
    }
    __syncthreads();

    // claim global space per non-empty bucket
    for (int b = t; b < NB; b += 256) {
        int c = cntL[b];
        gposL[b] = c ? atomicAdd(&gcur[b], c) : 0;
    }
    __syncthreads();

    // flat lane-efficient copy-out (runs of ~2.6 records land contiguous per bucket)
    for (int i = t; i < tot; i += 256) {
        unsigned int r = sortedL[i];
        int bkt = bucketOf[i];
        binned[(size_t)bkt * BCAP + gposL[bkt] + (i - excL[bkt])] = r;
    }
}

// ---------------- scan bucket counts -> bucket base offsets ----------------

__global__ void scanB_k(const int* __restrict__ gcur, int* __restrict__ bbase,
                        int* __restrict__ rowptr) {
    __shared__ int s[1024];
    int t = threadIdx.x;
    int v = (t < NB) ? gcur[t] : 0;
    s[t] = v; __syncthreads();
    for (int off = 1; off < 1024; off <<= 1) {
        int x = (t >= off) ? s[t - off] : 0;
        __syncthreads();
        s[t] += x;
        __syncthreads();
    }
    if (t < NB) bbase[t] = s[t] - v;
    if (t == 0) { bbase[NB] = N_EDGES; rowptr[N_NODES] = N_EDGES; }
}

// ---------------- Phase B: per-fine-bucket CSR finalize, sorted by (node, src_chunk) ----------------

__global__ __launch_bounds__(256) void binB_k(
    const unsigned int* __restrict__ binned, const int* __restrict__ gcur,
    const int* __restrict__ bbase, int* __restrict__ rowptr,
    float* __restrict__ dinv, int* __restrict__ colv)
{
    __shared__ unsigned int recL[BCAP];   // 10 KB
    __shared__ int colL[BCAP];            // 10 KB
    __shared__ int hist[2048];            // 8 KB: key = (localnode<<4) | src_chunk
    __shared__ int partial[256];

    int b = blockIdx.x, t = threadIdx.x;
    int cnt = gcur[b];
    int base = bbase[b];
    const unsigned int* rp = binned + (size_t)b * BCAP;

    for (int i = t; i < 2048; i += 256) hist[i] = 0;
    __syncthreads();

    for (int i = t; i < cnt; i += 256) {
        unsigned int r = rp[i];
        recL[i] = r;
        unsigned int key = ((r & 127u) << 4) | src_chunk(r >> 7);
        atomicAdd(&hist[key], 1);
    }
    __syncthreads();

    // in-place exclusive scan of hist[2048]: 8/thread + block scan
    int base8 = t * 8;
    int v[8], lsum = 0;
#pragma unroll
    for (int j = 0; j < 8; j++) { v[j] = hist[base8 + j]; lsum += v[j]; }
    partial[t] = lsum;
    __syncthreads();
    for (int off = 1; off < 256; off <<= 1) {
        int x = (t >= off) ? partial[t - off] : 0;
        __syncthreads();
        partial[t] += x;
        __syncthreads();
    }
    int run = partial[t] - lsum;
#pragma unroll
    for (int j = 0; j < 8; j++) { hist[base8 + j] = run; run += v[j]; }
    __syncthreads();

    // rowptr & dinv from node boundaries (before scatter mutates hist)
    if (t < NPB) {
        int node = b * NPB + t;
        if (node < N_NODES) {
            int start = hist[t << 4];
            int end = (t < NPB - 1) ? hist[(t + 1) << 4] : cnt;
            rowptr[node] = base + start;
            dinv[node] = rsqrtf((float)(end - start + 1));   // +1 self-loop
        }
    }
    __syncthreads();

    // scatter into (node, chunk)-sorted order
    for (int i = t; i < cnt; i += 256) {
        unsigned int r = recL[i];
        unsigned int key = ((r & 127u) << 4) | src_chunk(r >> 7);
        int pos = atomicAdd(&hist[key], 1);
        colL[pos] = (int)(r >> 7);
    }
    __syncthreads();
    for (int i = t; i < cnt; i += 256) colv[base + i] = colL[i];
}

// ---------------- weight convert: W[k][n] fp32 -> Wt[n][k] bf16 ----------------

__global__ void convw_k(const float* __restrict__ W0, const float* __restrict__ W1,
                        const float* __restrict__ W2,
                        unsigned short* __restrict__ Wt0, unsigned short* __restrict__ Wt1,
                        unsigned short* __restrict__ Wt2) {
    int i = blockIdx.x * 256 + threadIdx.x;
    if (i < 16384) {
        int n = i >> 7, k = i & 127;
        Wt0[i] = f2bf(W0[k * 128 + n]);
        Wt1[i] = f2bf(W1[k * 128 + n]);
    }
    if (i < 48 * 128) {
        int n = i >> 7, k = i & 127;
        Wt2[i] = (n < OUTD) ? f2bf(W2[k * OUTD + n]) : (unsigned short)0;
    }
}

// ---------------- MFMA GEMM (M x 128 @ 128 x N), fused BN+ReLU, dinv prescale ----------------

template <int ABF16, int MODE, int NT, int OBF16>
__global__ __launch_bounds__(256) void gemm_k(
    const void* __restrict__ Ap, const unsigned short* __restrict__ Wt,
    const float* __restrict__ bns, const float* __restrict__ bnt,
    const float* __restrict__ dinv, void* __restrict__ Outp,
    int ncols, int ostride)
{
    __shared__ unsigned short WtL[NT * 16][136];
    __shared__ float sS[128], sT[128];

    int t = threadIdx.x;
    if (MODE) { if (t < 128) { sS[t] = bns[t]; sT[t] = bnt[t]; } }

    const int TOT = NT * 16 * 128;
    for (int e = t * 8; e < TOT; e += 256 * 8) {
        int n = e >> 7, k = e & 127;
        uint4 v = *(const uint4*)(Wt + e);
        *(uint4*)&WtL[n][k] = v;
    }
    __syncthreads();

    int wave = t >> 6, lane = t & 63;
    int quad = lane >> 4, m16 = lane & 15;
    int rbase = blockIdx.x * 128 + wave * 32;

    f32x4 acc[2][NT];
#pragma unroll
    for (int rt = 0; rt < 2; rt++)
#pragma unroll
        for (int ct = 0; ct < NT; ct++) acc[rt][ct] = (f32x4){0.f, 0.f, 0.f, 0.f};

#pragma unroll
    for (int kc = 0; kc < 4; kc++) {
        int kb = kc * 32 + quad * 8;
        bf16x8 afrag[2];
#pragma unroll
        for (int rt = 0; rt < 2; rt++) {
            int row = rbase + rt * 16 + m16;
            bool rv = (row < N_NODES);
            if (ABF16) {
                uint4 v = make_uint4(0, 0, 0, 0);
                if (rv) v = *(const uint4*)((const unsigned short*)Ap + (size_t)row * 128 + kb);
                if (MODE) {
                    unsigned int uu[4] = {v.x, v.y, v.z, v.w};
                    unsigned short* fp = (unsigned short*)&afrag[rt];
#pragma unroll
                    for (int i = 0; i < 4; i++) {
                        int k0 = kb + 2 * i;
                        float lo = fmaxf(bf_lo(uu[i]) * sS[k0] + sT[k0], 0.f);
                        float hi = fmaxf(bf_hi(uu[i]) * sS[k0 + 1] + sT[k0 + 1], 0.f);
                        fp[2 * i] = f2bf(lo);
                        fp[2 * i + 1] = f2bf(hi);
                    }
                } else {
                    afrag[rt] = *(bf16x8*)&v;
                }
            } else {
                const float* ap = (const float*)Ap + (size_t)row * 128 + kb;
                float4 f0 = make_float4(0.f, 0.f, 0.f, 0.f), f1 = f0;
                if (rv) { f0 = *(const float4*)ap; f1 = *(const float4*)(ap + 4); }
                unsigned short* fp = (unsigned short*)&afrag[rt];
                fp[0] = f2bf(f0.x); fp[1] = f2bf(f0.y); fp[2] = f2bf(f0.z); fp[3] = f2bf(f0.w);
                fp[4] = f2bf(f1.x); fp[5] = f2bf(f1.y); fp[6] = f2bf(f1.z); fp[7] = f2bf(f1.w);
            }
        }
#pragma unroll
        for (int ct = 0; ct < NT; ct++) {
            bf16x8 bfrag = *(bf16x8*)&WtL[ct * 16 + m16][kb];
#pragma unroll
            for (int rt = 0; rt < 2; rt++)
                acc[rt][ct] = __builtin_amdgcn_mfma_f32_16x16x32_bf16(
                    afrag[rt], bfrag, acc[rt][ct], 0, 0, 0);
        }
    }

#pragma unroll
    for (int rt = 0; rt < 2; rt++)
#pragma unroll
        for (int r = 0; r < 4; r++) {
            int row = rbase + rt * 16 + quad * 4 + r;
            if (row < N_NODES) {
                float d = dinv[row];
#pragma unroll
                for (int ct = 0; ct < NT; ct++) {
                    int c = ct * 16 + m16;
                    if (c < ncols) {
                        float val = acc[rt][ct][r] * d;
                        if (OBF16)
                            ((unsigned short*)Outp)[(size_t)row * ostride + c] = f2bf(val);
                        else
                            ((float*)Outp)[(size_t)row * ostride + c] = val;
                    }
                }
            }
        }
}

// ---------------- Aggregation: one wave per dst node, bf16 rows (uint/lane) ----------------

__global__ __launch_bounds__(256) void agg_k(
    const unsigned int* __restrict__ H, const int* __restrict__ rowptr,
    const int* __restrict__ colv, const float* __restrict__ dinv,
    const float* __restrict__ bias, unsigned int* __restrict__ out)
{
    int gw = (blockIdx.x * 256 + threadIdx.x) >> 6;
    int lane = threadIdx.x & 63;
    if (gw >= N_NODES) return;
    int rp = rowptr[gw], re = rowptr[gw + 1];
    unsigned int self = H[gw * 64 + lane];   // self-loop (prescaled row)
    float ax = bf_lo(self), ay = bf_hi(self);
    for (int j0 = rp; j0 < re; j0 += 64) {
        int idx = (j0 + lane < re) ? colv[j0 + lane] : 0;
        int n = min(64, re - j0);
        int j = 0;
        for (; j + 3 < n; j += 4) {
            int s0 = __shfl(idx, j), s1 = __shfl(idx, j + 1);
            int s2 = __shfl(idx, j + 2), s3 = __shfl(idx, j + 3);
            unsigned int u0 = H[s0 * 64 + lane], u1 = H[s1 * 64 + lane];
            unsigned int u2 = H[s2 * 64 + lane], u3 = H[s3 * 64 + lane];
            ax += bf_lo(u0) + bf_lo(u1) + bf_lo(u2) + bf_lo(u3);
            ay += bf_hi(u0) + bf_hi(u1) + bf_hi(u2) + bf_hi(u3);
        }
        for (; j < n; j++) {
            int s = __shfl(idx, j);
            unsigned int u = H[s * 64 + lane];
            ax += bf_lo(u);
            ay += bf_hi(u);
        }
    }
    float d = dinv[gw];
    float2 b = ((const float2*)bias)[lane];
    unsigned short rx = f2bf(ax * d + b.x);
    unsigned short ry = f2bf(ay * d + b.y);
    out[gw * 64 + lane] = (unsigned int)rx | ((unsigned int)ry << 16);
}

// ---------------- Final aggregation (bf16 48-stride rows) + bias + log_softmax ----------------

__global__ __launch_bounds__(256) void agg_out_k(
    const unsigned int* __restrict__ H, const int* __restrict__ rowptr,
    const int* __restrict__ colv, const float* __restrict__ dinv,
    const float* __restrict__ b2, float* __restrict__ out)
{
    int gw = (blockIdx.x * 256 + threadIdx.x) >> 6;
    int lane = threadIdx.x & 63;
    if (gw >= N_NODES) return;
    bool ld = lane < 24;                  // 24 uints = 48 bf16 per row
    int c0 = lane * 2, c1 = lane * 2 + 1;
    int rp = rowptr[gw], re = rowptr[gw + 1];
    float ax = 0.f, ay = 0.f;
    if (ld) {
        unsigned int u = H[gw * 24 + lane];   // self (prescaled)
        ax = bf_lo(u); ay = bf_hi(u);
    }
    for (int j0 = rp; j0 < re; j0 += 64) {
        int idx = (j0 + lane < re) ? colv[j0 + lane] : 0;
        int n = min(64, re - j0);
        int j = 0;
        for (; j + 3 < n; j += 4) {
            int s0 = __shfl(idx, j), s1 = __shfl(idx, j + 1);
            int s2 = __shfl(idx, j + 2), s3 = __shfl(idx, j + 3);
            if (ld) {
                unsigned int u0 = H[s0 * 24 + lane], u1 = H[s1 * 24 + lane];
                unsigned int u2 = H[s2 * 24 + lane], u3 = H[s3 * 24 + lane];
                ax += bf_lo(u0) + bf_lo(u1) + bf_lo(u2) + bf_lo(u3);
                ay += bf_hi(u0) + bf_hi(u1) + bf_hi(u2) + bf_hi(u3);
            }
        }
        for (; j < n; j++) {
            int s = __shfl(idx, j);
            if (ld) {
                unsigned int u = H[s * 24 + lane];
                ax += bf_lo(u);
                ay += bf_hi(u);
            }
        }
    }
    float d = dinv[gw];
    float v0 = -INFINITY, v1 = -INFINITY;
    if (ld) {
        v0 = ax * d + b2[c0];
        if (c1 < OUTD) v1 = ay * d + b2[c1];
    }
    float m = fmaxf(v0, v1);
    for (int off = 16; off; off >>= 1) m = fmaxf(m, __shfl_xor(m, off));
    float e = 0.f;
    if (ld) {
        e = __expf(v0 - m);
        if (c1 < OUTD) e += __expf(v1 - m);
    }
    float sum = e;
    for (int off = 16; off; off >>= 1) sum += __shfl_xor(sum, off);
    float ls = logf(sum);
    if (ld) {
        out[(size_t)gw * OUTD + c0] = v0 - m - ls;
        if (c1 < OUTD) out[(size_t)gw * OUTD + c1] = v1 - m - ls;
    }
}

// ---------------- BatchNorm stats (bf16 input) ----------------

__global__ __launch_bounds__(256) void bnstats_k(const unsigned int* __restrict__ H,
                                                 float* __restrict__ sum,
                                                 float* __restrict__ sq)
{
    __shared__ float2 ls[256], lq[256];
    int t = threadIdx.x;
    int idx = blockIdx.x * 256 + t;
    int stride = gridDim.x * 256;
    float sx = 0.f, sy = 0.f, qx = 0.f, qy = 0.f;
    for (; idx < N_NODES * 64; idx += stride) {
        unsigned int u = H[idx];
        float x = bf_lo(u), y = bf_hi(u);
        sx += x; sy += y; qx += x * x; qy += y * y;
    }
    ls[t] = make_float2(sx, sy);
    lq[t] = make_float2(qx, qy);
    __syncthreads();
    if (t < 64) {
        float2 a = ls[t], b = ls[t + 64], c = ls[t + 128], d = ls[t + 192];
        float2 e = lq[t], f = lq[t + 64], g = lq[t + 128], h = lq[t + 192];
        int c0 = t * 2;
        atomicAdd(&sum[c0],     a.x + b.x + c.x + d.x);
        atomicAdd(&sum[c0 + 1], a.y + b.y + c.y + d.y);
        atomicAdd(&sq[c0],      e.x + f.x + g.x + h.x);
        atomicAdd(&sq[c0 + 1],  e.y + f.y + g.y + h.y);
    }
}

__global__ void bnfinal_k(const float* __restrict__ sum, const float* __restrict__ sq,
                          const float* __restrict__ g, const float* __restrict__ be,
                          float* __restrict__ bs, float* __restrict__ bt)
{
    int c = threadIdx.x;
    if (c < 128) {
        float mean = sum[c] * (1.0f / N_NODES);
        float var = sq[c] * (1.0f / N_NODES) - mean * mean;
        float inv = rsqrtf(var + 1e-5f);
        float s = g[c] * inv;
        bs[c] = s;
        bt[c] = be[c] - mean * s;
    }
}

// ---------------- launch ----------------

extern "C" void kernel_launch(void* const* d_in, const int* in_sizes, int n_in,
                              void* d_out, int out_size, void* d_ws, size_t ws_size,
                              hipStream_t stream)
{
    const float* x   = (const float*)d_in[0];
    const int*   ei  = (const int*)d_in[1];
    const float* W0  = (const float*)d_in[2];
    const float* b0  = (const float*)d_in[3];
    const float* W1  = (const float*)d_in[4];
    const float* b1  = (const float*)d_in[5];
    const float* W2  = (const float*)d_in[6];
    const float* b2  = (const float*)d_in[7];
    const float* g0  = (const float*)d_in[8];
    const float* be0 = (const float*)d_in[9];
    const float* g1  = (const float*)d_in[10];
    const float* be1 = (const float*)d_in[11];
    const int* srcv = ei;
    const int* dstv = ei + N_EDGES;

    char* w = (char*)d_ws;
    unsigned int* H0 = (unsigned int*)w;  w += (size_t)N_NODES * 128 * 2;   // bf16 [N][128]
    unsigned int* H1 = (unsigned int*)w;  w += (size_t)N_NODES * 128 * 2;   // bf16 [N][128]
    unsigned int* Hf = (unsigned int*)w;  w += (size_t)N_NODES * OSTR * 2;  // bf16 [N][48]
    unsigned int* binned = (unsigned int*)w; w += (size_t)NB * BCAP * 4;    // 8.0 MB
    unsigned short* Wt0 = (unsigned short*)w; w += 16384 * 2;
    unsigned short* Wt1 = (unsigned short*)w; w += 16384 * 2;
    unsigned short* Wt2 = (unsigned short*)w; w += 48 * 128 * 2;
    int* gcur = (int*)w;        w += (size_t)(NB + 2) * 4;
    int* bbase = (int*)w;       w += (size_t)(NB + 2) * 4;
    int* rowptr = (int*)w;      w += (size_t)(N_NODES + 4) * 4;
    int* colv = (int*)w;        w += (size_t)N_EDGES * 4;
    float* dinv = (float*)w;    w += (size_t)N_NODES * 4;
    float* bnS = (float*)w;     w += 128 * 4;
    float* bnQ = (float*)w;     w += 128 * 4;
    float* bns = (float*)w;     w += 128 * 4;
    float* bnt = (float*)w;     w += 128 * 4;

    int gb = (N_NODES + 127) / 128;       // 782
    int ab = (N_NODES * 64 + 255) / 256;  // 25000

    hipMemsetAsync(gcur, 0, (size_t)NB * 4, stream);

    convw_k<<<64, 256, 0, stream>>>(W0, W1, W2, Wt0, Wt1, Wt2);
    binA_k<<<NCHB, 256, 0, stream>>>(srcv, dstv, gcur, binned);
    scanB_k<<<1, 1024, 0, stream>>>(gcur, bbase, rowptr);
    binB_k<<<NB, 256, 0, stream>>>(binned, gcur, bbase, rowptr, dinv, colv);

    // Layer 0: x fp32 -> H0 bf16 (dinv-prescaled)
    gemm_k<0, 0, 8, 1><<<gb, 256, 0, stream>>>(x, Wt0, nullptr, nullptr, dinv, H0, 128, 128);
    agg_k<<<ab, 256, 0, stream>>>(H0, rowptr, colv, dinv, b0, H1);
    hipMemsetAsync(bnS, 0, 128 * 4 * 2, stream);
    bnstats_k<<<512, 256, 0, stream>>>(H1, bnS, bnQ);
    bnfinal_k<<<1, 128, 0, stream>>>(bnS, bnQ, g0, be0, bns, bnt);

    // Layer 1: BN+ReLU fused into A-load, bf16 MFMA
    gemm_k<1, 1, 8, 1><<<gb, 256, 0, stream>>>(H1, Wt1, bns, bnt, dinv, H0, 128, 128);
    agg_k<<<ab, 256, 0, stream>>>(H0, rowptr, colv, dinv, b1, H1);
    hipMemsetAsync(bnS, 0, 128 * 4 * 2, stream);
    bnstats_k<<<512, 256, 0, stream>>>(H1, bnS, bnQ);
    bnfinal_k<<<1, 128, 0, stream>>>(bnS, bnQ, g1, be1, bns, bnt);

    // Layer 2: 47-wide out (bf16, stride 48) + fused log_softmax aggregation
    gemm_k<1, 1, 3, 1><<<gb, 256, 0, stream>>>(H1, Wt2, bns, bnt, dinv, Hf, OUTD, OSTR);
    agg_out_k<<<ab, 256, 0, stream>>>(Hf, rowptr, colv, dinv, b2, (float*)d_out);
}

// Round 5
// 483.540 us; speedup vs baseline: 1.9690x; 1.0746x over previous
//
#include <hip/hip_runtime.h>
#include <math.h>

#define N_NODES 100000
#define N_EDGES 1600000
#define HID 128
#define OUTD 47
#define OSTR 48

#define NPB 128                       // nodes per fine bucket
#define NB 782                        // ceil(100000/128)
#define BCAP 2560                     // record capacity per fine bucket (mean 2046, max ~2300)
#define CHUNK 2048                    // edges per phase-A block
#define NCHB 782                      // phase-A binning blocks
#define CWB 64                        // convw blocks appended to binA grid

typedef short bf16x8 __attribute__((ext_vector_type(8)));
typedef float f32x4 __attribute__((ext_vector_type(4)));

__device__ inline unsigned short f2bf(float x) {
    union { float f; unsigned int u; } v; v.f = x;
    unsigned int r = v.u + 0x7fffu + ((v.u >> 16) & 1u);   // RNE
    return (unsigned short)(r >> 16);
}
__device__ inline float bf_lo(unsigned int u) { return __uint_as_float(u << 16); }
__device__ inline float bf_hi(unsigned int u) { return __uint_as_float(u & 0xffff0000u); }

// src-chunk for gather locality: 16 chunks of 6250 nodes
__device__ inline unsigned int src_chunk(unsigned int s) {
    return (s * 42950u) >> 28;   // == s / 6250 for s < 100000
}

// ---------------- Phase A: bin edges by dst fine-bucket + (appended blocks) weight convert ----------------

__global__ __launch_bounds__(256) void binA_k(
    const int* __restrict__ src, const int* __restrict__ dst,
    int* __restrict__ gcur, unsigned int* __restrict__ binned,
    const float* __restrict__ W0, const float* __restrict__ W1, const float* __restrict__ W2,
    unsigned short* __restrict__ Wt0, unsigned short* __restrict__ Wt1,
    unsigned short* __restrict__ Wt2)
{
    __shared__ unsigned int sortedL[CHUNK];       // 8 KB
    __shared__ unsigned short bucketOf[CHUNK];    // 4 KB
    __shared__ int cntL[NB];
    __shared__ int excL[NB];
    __shared__ int curL[NB];
    __shared__ int gposL[NB];
    __shared__ int partial[256];

    int t = threadIdx.x;

    if (blockIdx.x >= NCHB) {
        // weight-convert tail blocks
        int i = (blockIdx.x - NCHB) * 256 + t;
        if (i < 16384) {
            int n = i >> 7, k = i & 127;
            Wt0[i] = f2bf(W0[k * 128 + n]);
            Wt1[i] = f2bf(W1[k * 128 + n]);
        }
        if (i < 48 * 128) {
            int n = i >> 7, k = i & 127;
            Wt2[i] = (n < OUTD) ? f2bf(W2[k * OUTD + n]) : (unsigned short)0;
        }
        return;
    }

    int e0 = blockIdx.x * CHUNK;

    for (int i = t; i < NB; i += 256) cntL[i] = 0;
    __syncthreads();

    for (int i = t; i < CHUNK; i += 256) {
        int e = e0 + i;
        if (e < N_EDGES) atomicAdd(&cntL[dst[e] >> 7], 1);
    }
    __syncthreads();

    // exclusive scan of cntL[NB]
    int b4 = t * 4;
    int c0 = (b4 + 0 < NB) ? cntL[b4 + 0] : 0;
    int c1 = (b4 + 1 < NB) ? cntL[b4 + 1] : 0;
    int c2 = (b4 + 2 < NB) ? cntL[b4 + 2] : 0;
    int c3 = (b4 + 3 < NB) ? cntL[b4 + 3] : 0;
    int lsum = c0 + c1 + c2 + c3;
    partial[t] = lsum;
    __syncthreads();
    for (int off = 1; off < 256; off <<= 1) {
        int x = (t >= off) ? partial[t - off] : 0;
        __syncthreads();
        partial[t] += x;
        __syncthreads();
    }
    int pbase = partial[t] - lsum;
    if (b4 + 0 < NB) { excL[b4 + 0] = pbase;                curL[b4 + 0] = pbase; }
    if (b4 + 1 < NB) { excL[b4 + 1] = pbase + c0;           curL[b4 + 1] = pbase + c0; }
    if (b4 + 2 < NB) { excL[b4 + 2] = pbase + c0 + c1;      curL[b4 + 2] = pbase + c0 + c1; }
    if (b4 + 3 < NB) { excL[b4 + 3] = pbase + c0 + c1 + c2; curL[b4 + 3] = pbase + c0 + c1 + c2; }
    __syncthreads();

    int tot = partial[255];

    for (int i = t; i < CHUNK; i += 256) {
        int e = e0 + i;
        if (e < N_EDGES) {
            int d = dst[e];
            int s = src[e];
            int bkt = d >> 7;
            int pos = atomicAdd(&curL[bkt], 1);
            sortedL[pos] = ((unsigned int)s << 7) | (unsigned int)(d & 127);
            bucketOf[pos] = (unsigned short)bkt;
        }
    }
    __syncthreads();

    for (int b = t; b < NB; b += 256) {
        int c = cntL[b];
        gposL[b] = c ? atomicAdd(&gcur[b], c) : 0;
    }
    __syncthreads();

    for (int i = t; i < tot; i += 256) {
        unsigned int r = sortedL[i];
        int bkt = bucketOf[i];
        binned[(size_t)bkt * BCAP + gposL[bkt] + (i - excL[bkt])] = r;
    }
}

// ---------------- Phase B: per-fine-bucket CSR finalize into fixed regions ----------------

__global__ __launch_bounds__(256) void binB_k(
    const unsigned int* __restrict__ binned, const int* __restrict__ gcur,
    int2* __restrict__ rowse, float* __restrict__ dinv, int* __restrict__ colv)
{
    __shared__ unsigned int recL[BCAP];   // 10 KB
    __shared__ int colL[BCAP];            // 10 KB
    __shared__ int hist[2048];            // 8 KB: key = (localnode<<4) | src_chunk
    __shared__ int partial[256];

    int b = blockIdx.x, t = threadIdx.x;
    int cnt = gcur[b];
    int base = b * BCAP;
    const unsigned int* rp = binned + (size_t)b * BCAP;

    for (int i = t; i < 2048; i += 256) hist[i] = 0;
    __syncthreads();

    for (int i = t; i < cnt; i += 256) {
        unsigned int r = rp[i];
        recL[i] = r;
        unsigned int key = ((r & 127u) << 4) | src_chunk(r >> 7);
        atomicAdd(&hist[key], 1);
    }
    __syncthreads();

    // in-place exclusive scan of hist[2048]
    int base8 = t * 8;
    int v[8], lsum = 0;
#pragma unroll
    for (int j = 0; j < 8; j++) { v[j] = hist[base8 + j]; lsum += v[j]; }
    partial[t] = lsum;
    __syncthreads();
    for (int off = 1; off < 256; off <<= 1) {
        int x = (t >= off) ? partial[t - off] : 0;
        __syncthreads();
        partial[t] += x;
        __syncthreads();
    }
    int run = partial[t] - lsum;
#pragma unroll
    for (int j = 0; j < 8; j++) { hist[base8 + j] = run; run += v[j]; }
    __syncthreads();

    if (t < NPB) {
        int node = b * NPB + t;
        if (node < N_NODES) {
            int start = hist[t << 4];
            int end = (t < NPB - 1) ? hist[(t + 1) << 4] : cnt;
            rowse[node] = make_int2(base + start, base + end);
            dinv[node] = rsqrtf((float)(end - start + 1));   // +1 self-loop
        }
    }
    __syncthreads();

    for (int i = t; i < cnt; i += 256) {
        unsigned int r = recL[i];
        unsigned int key = ((r & 127u) << 4) | src_chunk(r >> 7);
        int pos = atomicAdd(&hist[key], 1);
        colL[pos] = (int)(r >> 7);
    }
    __syncthreads();
    for (int i = t; i < cnt; i += 256) colv[base + i] = colL[i];
}

// ---------------- MFMA GEMM (M x 128 @ 128 x N), fused BN-final+BN-apply+ReLU, dinv prescale ----------------

template <int ABF16, int MODE, int NT, int OBF16>
__global__ __launch_bounds__(256) void gemm_k(
    const void* __restrict__ Ap, const unsigned short* __restrict__ Wt,
    const float* __restrict__ bnSum, const float* __restrict__ bnSq,
    const float* __restrict__ gam, const float* __restrict__ bet,
    const float* __restrict__ dinv, void* __restrict__ Outp,
    int ncols, int ostride)
{
    __shared__ unsigned short WtL[NT * 16][136];
    __shared__ float sS[128], sT[128];

    int t = threadIdx.x;
    if (MODE) {
        if (t < 128) {
            float mean = bnSum[t] * (1.0f / N_NODES);
            float var = bnSq[t] * (1.0f / N_NODES) - mean * mean;
            float inv = rsqrtf(var + 1e-5f);
            float s = gam[t] * inv;
            sS[t] = s;
            sT[t] = bet[t] - mean * s;
        }
    }

    const int TOT = NT * 16 * 128;
    for (int e = t * 8; e < TOT; e += 256 * 8) {
        int n = e >> 7, k = e & 127;
        uint4 v = *(const uint4*)(Wt + e);
        *(uint4*)&WtL[n][k] = v;
    }
    __syncthreads();

    int wave = t >> 6, lane = t & 63;
    int quad = lane >> 4, m16 = lane & 15;
    int rbase = blockIdx.x * 128 + wave * 32;

    f32x4 acc[2][NT];
#pragma unroll
    for (int rt = 0; rt < 2; rt++)
#pragma unroll
        for (int ct = 0; ct < NT; ct++) acc[rt][ct] = (f32x4){0.f, 0.f, 0.f, 0.f};

#pragma unroll
    for (int kc = 0; kc < 4; kc++) {
        int kb = kc * 32 + quad * 8;
        bf16x8 afrag[2];
#pragma unroll
        for (int rt = 0; rt < 2; rt++) {
            int row = rbase + rt * 16 + m16;
            bool rv = (row < N_NODES);
            if (ABF16) {
                uint4 v = make_uint4(0, 0, 0, 0);
                if (rv) v = *(const uint4*)((const unsigned short*)Ap + (size_t)row * 128 + kb);
                if (MODE) {
                    unsigned int uu[4] = {v.x, v.y, v.z, v.w};
                    unsigned short* fp = (unsigned short*)&afrag[rt];
#pragma unroll
                    for (int i = 0; i < 4; i++) {
                        int k0 = kb + 2 * i;
                        float lo = fmaxf(bf_lo(uu[i]) * sS[k0] + sT[k0], 0.f);
                        float hi = fmaxf(bf_hi(uu[i]) * sS[k0 + 1] + sT[k0 + 1], 0.f);
                        fp[2 * i] = f2bf(lo);
                        fp[2 * i + 1] = f2bf(hi);
                    }
                } else {
                    afrag[rt] = *(bf16x8*)&v;
                }
            } else {
                const float* ap = (const float*)Ap + (size_t)row * 128 + kb;
                float4 f0 = make_float4(0.f, 0.f, 0.f, 0.f), f1 = f0;
                if (rv) { f0 = *(const float4*)ap; f1 = *(const float4*)(ap + 4); }
                unsigned short* fp = (unsigned short*)&afrag[rt];
                fp[0] = f2bf(f0.x); fp[1] = f2bf(f0.y); fp[2] = f2bf(f0.z); fp[3] = f2bf(f0.w);
                fp[4] = f2bf(f1.x); fp[5] = f2bf(f1.y); fp[6] = f2bf(f1.z); fp[7] = f2bf(f1.w);
            }
        }
#pragma unroll
        for (int ct = 0; ct < NT; ct++) {
            bf16x8 bfrag = *(bf16x8*)&WtL[ct * 16 + m16][kb];
#pragma unroll
            for (int rt = 0; rt < 2; rt++)
                acc[rt][ct] = __builtin_amdgcn_mfma_f32_16x16x32_bf16(
                    afrag[rt], bfrag, acc[rt][ct], 0, 0, 0);
        }
    }

#pragma unroll
    for (int rt = 0; rt < 2; rt++)
#pragma unroll
        for (int r = 0; r < 4; r++) {
            int row = rbase + rt * 16 + quad * 4 + r;
            if (row < N_NODES) {
                float d = dinv[row];
#pragma unroll
                for (int ct = 0; ct < NT; ct++) {
                    int c = ct * 16 + m16;
                    if (c < ncols) {
                        float val = acc[rt][ct][r] * d;
                        if (OBF16)
                            ((unsigned short*)Outp)[(size_t)row * ostride + c] = f2bf(val);
                        else
                            ((float*)Outp)[(size_t)row * ostride + c] = val;
                    }
                }
            }
        }
}

// ---------------- Aggregation: one wave per dst node, half-wave per record, uint2/lane ----------------

__global__ __launch_bounds__(256) void agg_k(
    const unsigned int* __restrict__ H, const int2* __restrict__ rowse,
    const int* __restrict__ colv, const float* __restrict__ dinv,
    const float* __restrict__ bias, unsigned int* __restrict__ out)
{
    int gw = (blockIdx.x * 256 + threadIdx.x) >> 6;
    int lane = threadIdx.x & 63;
    if (gw >= N_NODES) return;
    int half = lane >> 5;          // half-wave id: records 2t+half
    int c = lane & 31;             // uint2 index within row (covers channels 4c..4c+3)
    int2 se = rowse[gw];
    int rp = se.x, re = se.y;
    const uint2* H2 = (const uint2*)H;

    float a0 = 0.f, a1 = 0.f, a2 = 0.f, a3 = 0.f;
    if (half == 0) {               // self-loop (prescaled row)
        uint2 u = H2[(size_t)gw * 32 + c];
        a0 = bf_lo(u.x); a1 = bf_hi(u.x); a2 = bf_lo(u.y); a3 = bf_hi(u.y);
    }

    for (int j0 = rp; j0 < re; j0 += 64) {
        int idx = (j0 + lane < re) ? colv[j0 + lane] : 0;
        int n = min(64, re - j0);
        int np = n >> 1;
        int t2 = 0;
        for (; t2 + 1 < np; t2 += 2) {
            int sa = __shfl(idx, 2 * t2 + half);
            int sb = __shfl(idx, 2 * t2 + 2 + half);
            uint2 ua = H2[(size_t)sa * 32 + c];
            uint2 ub = H2[(size_t)sb * 32 + c];
            a0 += bf_lo(ua.x) + bf_lo(ub.x);
            a1 += bf_hi(ua.x) + bf_hi(ub.x);
            a2 += bf_lo(ua.y) + bf_lo(ub.y);
            a3 += bf_hi(ua.y) + bf_hi(ub.y);
        }
        if (t2 < np) {
            int sa = __shfl(idx, 2 * t2 + half);
            uint2 ua = H2[(size_t)sa * 32 + c];
            a0 += bf_lo(ua.x); a1 += bf_hi(ua.x);
            a2 += bf_lo(ua.y); a3 += bf_hi(ua.y);
        }
        if (n & 1) {               // odd tail record: half 0 only
            int sa = __shfl(idx, n - 1);
            if (half == 0) {
                uint2 ua = H2[(size_t)sa * 32 + c];
                a0 += bf_lo(ua.x); a1 += bf_hi(ua.x);
                a2 += bf_lo(ua.y); a3 += bf_hi(ua.y);
            }
        }
    }

    // combine the two half-wave accumulators
    a0 += __shfl_xor(a0, 32);
    a1 += __shfl_xor(a1, 32);
    a2 += __shfl_xor(a2, 32);
    a3 += __shfl_xor(a3, 32);

    if (half == 0) {
        float d = dinv[gw];
        float4 b = ((const float4*)bias)[c];
        uint2 r;
        r.x = (unsigned int)f2bf(a0 * d + b.x) | ((unsigned int)f2bf(a1 * d + b.y) << 16);
        r.y = (unsigned int)f2bf(a2 * d + b.z) | ((unsigned int)f2bf(a3 * d + b.w) << 16);
        ((uint2*)out)[(size_t)gw * 32 + c] = r;
    }
}

// ---------------- Final aggregation (bf16 48-stride rows), half-wave per record + log_softmax ----------------

__global__ __launch_bounds__(256) void agg_out_k(
    const unsigned int* __restrict__ H, const int2* __restrict__ rowse,
    const int* __restrict__ colv, const float* __restrict__ dinv,
    const float* __restrict__ b2, float* __restrict__ out)
{
    int gw = (blockIdx.x * 256 + threadIdx.x) >> 6;
    int lane = threadIdx.x & 63;
    if (gw >= N_NODES) return;
    int half = lane >> 5;
    int c = lane & 31;
    bool ld = c < 24;              // 24 uints = 48 bf16 per row
    int2 se = rowse[gw];
    int rp = se.x, re = se.y;

    float ax = 0.f, ay = 0.f;
    if (half == 0 && ld) {
        unsigned int u = H[(size_t)gw * 24 + c];   // self (prescaled)
        ax = bf_lo(u); ay = bf_hi(u);
    }

    for (int j0 = rp; j0 < re; j0 += 64) {
        int idx = (j0 + lane < re) ? colv[j0 + lane] : 0;
        int n = min(64, re - j0);
        int np = n >> 1;
        int t2 = 0;
        for (; t2 + 1 < np; t2 += 2) {
            int sa = __shfl(idx, 2 * t2 + half);
            int sb = __shfl(idx, 2 * t2 + 2 + half);
            if (ld) {
                unsigned int ua = H[(size_t)sa * 24 + c];
                unsigned int ub = H[(size_t)sb * 24 + c];
                ax += bf_lo(ua) + bf_lo(ub);
                ay += bf_hi(ua) + bf_hi(ub);
            }
        }
        if (t2 < np) {
            int sa = __shfl(idx, 2 * t2 + half);
            if (ld) {
                unsigned int ua = H[(size_t)sa * 24 + c];
                ax += bf_lo(ua); ay += bf_hi(ua);
            }
        }
        if (n & 1) {
            int sa = __shfl(idx, n - 1);
            if (half == 0 && ld) {
                unsigned int ua = H[(size_t)sa * 24 + c];
                ax += bf_lo(ua); ay += bf_hi(ua);
            }
        }
    }

    ax += __shfl_xor(ax, 32);
    ay += __shfl_xor(ay, 32);

    float d = dinv[gw];
    int c0 = c * 2, c1 = c * 2 + 1;
    float v0 = -INFINITY, v1 = -INFINITY;
    if (ld) {
        v0 = ax * d + b2[c0];
        if (c1 < OUTD) v1 = ay * d + b2[c1];
    }
    float m = fmaxf(v0, v1);
    for (int off = 16; off; off >>= 1) m = fmaxf(m, __shfl_xor(m, off));
    float e = 0.f;
    if (ld) {
        e = __expf(v0 - m);
        if (c1 < OUTD) e += __expf(v1 - m);
    }
    float sum = e;
    for (int off = 16; off; off >>= 1) sum += __shfl_xor(sum, off);
    float ls = logf(sum);
    if (half == 0 && ld) {
        out[(size_t)gw * OUTD + c0] = v0 - m - ls;
        if (c1 < OUTD) out[(size_t)gw * OUTD + c1] = v1 - m - ls;
    }
}

// ---------------- BatchNorm stats (bf16 input) ----------------

__global__ __launch_bounds__(256) void bnstats_k(const unsigned int* __restrict__ H,
                                                 float* __restrict__ sum,
                                                 float* __restrict__ sq)
{
    __shared__ float2 ls[256], lq[256];
    int t = threadIdx.x;
    int idx = blockIdx.x * 256 + t;
    int stride = gridDim.x * 256;
    float sx = 0.f, sy = 0.f, qx = 0.f, qy = 0.f;
    for (; idx < N_NODES * 64; idx += stride) {
        unsigned int u = H[idx];
        float x = bf_lo(u), y = bf_hi(u);
        sx += x; sy += y; qx += x * x; qy += y * y;
    }
    ls[t] = make_float2(sx, sy);
    lq[t] = make_float2(qx, qy);
    __syncthreads();
    if (t < 64) {
        float2 a = ls[t], b = ls[t + 64], c = ls[t + 128], d = ls[t + 192];
        float2 e = lq[t], f = lq[t + 64], g = lq[t + 128], h = lq[t + 192];
        int c0 = t * 2;
        atomicAdd(&sum[c0],     a.x + b.x + c.x + d.x);
        atomicAdd(&sum[c0 + 1], a.y + b.y + c.y + d.y);
        atomicAdd(&sq[c0],      e.x + f.x + g.x + h.x);
        atomicAdd(&sq[c0 + 1],  e.y + f.y + g.y + h.y);
    }
}

// ---------------- launch ----------------

extern "C" void kernel_launch(void* const* d_in, const int* in_sizes, int n_in,
                              void* d_out, int out_size, void* d_ws, size_t ws_size,
                              hipStream_t stream)
{
    const float* x   = (const float*)d_in[0];
    const int*   ei  = (const int*)d_in[1];
    const float* W0  = (const float*)d_in[2];
    const float* b0  = (const float*)d_in[3];
    const float* W1  = (const float*)d_in[4];
    const float* b1  = (const float*)d_in[5];
    const float* W2  = (const float*)d_in[6];
    const float* b2  = (const float*)d_in[7];
    const float* g0  = (const float*)d_in[8];
    const float* be0 = (const float*)d_in[9];
    const float* g1  = (const float*)d_in[10];
    const float* be1 = (const float*)d_in[11];
    const int* srcv = ei;
    const int* dstv = ei + N_EDGES;

    char* w = (char*)d_ws;
    unsigned int* H0 = (unsigned int*)w;  w += (size_t)N_NODES * 128 * 2;   // bf16 [N][128]
    unsigned int* H1 = (unsigned int*)w;  w += (size_t)N_NODES * 128 * 2;   // bf16 [N][128]
    unsigned int* Hf = (unsigned int*)w;  w += (size_t)N_NODES * OSTR * 2;  // bf16 [N][48]
    unsigned int* binned = (unsigned int*)w; w += (size_t)NB * BCAP * 4;    // 8.0 MB
    int* colv = (int*)w;        w += (size_t)NB * BCAP * 4;                 // 8.0 MB (fixed regions)
    unsigned short* Wt0 = (unsigned short*)w; w += 16384 * 2;
    unsigned short* Wt1 = (unsigned short*)w; w += 16384 * 2;
    unsigned short* Wt2 = (unsigned short*)w; w += 48 * 128 * 2;
    int2* rowse = (int2*)w;     w += (size_t)N_NODES * 8;
    float* dinv = (float*)w;    w += (size_t)N_NODES * 4;
    // single-memset region: gcur (784 ints) + bnS0,bnQ0,bnS1,bnQ1 (512 floats)
    int* gcur = (int*)w;        w += 784 * 4;
    float* bnS0 = (float*)w;    w += 128 * 4;
    float* bnQ0 = (float*)w;    w += 128 * 4;
    float* bnS1 = (float*)w;    w += 128 * 4;
    float* bnQ1 = (float*)w;    w += 128 * 4;

    int gb = (N_NODES + 127) / 128;       // 782
    int ab = (N_NODES * 64 + 255) / 256;  // 25000

    hipMemsetAsync(gcur, 0, (784 + 512) * 4, stream);

    binA_k<<<NCHB + CWB, 256, 0, stream>>>(srcv, dstv, gcur, binned,
                                           W0, W1, W2, Wt0, Wt1, Wt2);
    binB_k<<<NB, 256, 0, stream>>>(binned, gcur, rowse, dinv, colv);

    // Layer 0: x fp32 -> H0 bf16 (dinv-prescaled)
    gemm_k<0, 0, 8, 1><<<gb, 256, 0, stream>>>(x, Wt0, nullptr, nullptr, nullptr, nullptr,
                                               dinv, H0, 128, 128);
    agg_k<<<ab, 256, 0, stream>>>(H0, rowse, colv, dinv, b0, H1);
    bnstats_k<<<512, 256, 0, stream>>>(H1, bnS0, bnQ0);

    // Layer 1: BN-final+BN-apply+ReLU fused into gemm, bf16 MFMA
    gemm_k<1, 1, 8, 1><<<gb, 256, 0, stream>>>(H1, Wt1, bnS0, bnQ0, g0, be0,
                                               dinv, H0, 128, 128);
    agg_k<<<ab, 256, 0, stream>>>(H0, rowse, colv, dinv, b1, H1);
    bnstats_k<<<512, 256, 0, stream>>>(H1, bnS1, bnQ1);

    // Layer 2: 47-wide out (bf16, stride 48) + fused log_softmax aggregation
    gemm_k<1, 1, 3, 1><<<gb, 256, 0, stream>>>(H1, Wt2, bnS1, bnQ1, g1, be1,
                                               dinv, Hf, OUTD, OSTR);
    agg_out_k<<<ab, 256, 0, stream>>>(Hf, rowse, colv, dinv, b2, (float*)d_out);
}

// Round 6
// 470.544 us; speedup vs baseline: 2.0234x; 1.0276x over previous
//
#include <hip/hip_runtime.h>
#include <math.h>

#define N_NODES 100000
#define N_EDGES 1600000
#define HID 128
#define OUTD 47
#define OSTR 48

#define NPB 128                       // nodes per fine bucket
#define NB 782                        // ceil(100000/128)
#define BCAP 2560                     // record capacity per fine bucket (mean 2046, max ~2300)
#define CHUNK 2048                    // edges per phase-A block
#define NCHB 782                      // phase-A binning blocks
#define CWB 64                        // convw blocks appended to binA grid

typedef short bf16x8 __attribute__((ext_vector_type(8)));
typedef float f32x4 __attribute__((ext_vector_type(4)));

__device__ inline unsigned short f2bf(float x) {
    union { float f; unsigned int u; } v; v.f = x;
    unsigned int r = v.u + 0x7fffu + ((v.u >> 16) & 1u);   // RNE
    return (unsigned short)(r >> 16);
}
__device__ inline float bf_lo(unsigned int u) { return __uint_as_float(u << 16); }
__device__ inline float bf_hi(unsigned int u) { return __uint_as_float(u & 0xffff0000u); }

// src-chunk for gather locality: 16 chunks of 6250 nodes
__device__ inline unsigned int src_chunk(unsigned int s) {
    return (s * 42950u) >> 28;   // == s / 6250 for s < 100000
}

// ---------------- Phase A: bin edges by dst fine-bucket + (appended blocks) weight convert ----------------

__global__ __launch_bounds__(256) void binA_k(
    const int* __restrict__ src, const int* __restrict__ dst,
    int* __restrict__ gcur, unsigned int* __restrict__ binned,
    const float* __restrict__ W0, const float* __restrict__ W1, const float* __restrict__ W2,
    unsigned short* __restrict__ Wt0, unsigned short* __restrict__ Wt1,
    unsigned short* __restrict__ Wt2)
{
    __shared__ unsigned int sortedL[CHUNK];       // 8 KB
    __shared__ unsigned short bucketOf[CHUNK];    // 4 KB
    __shared__ int cntL[NB];
    __shared__ int excL[NB];
    __shared__ int curL[NB];
    __shared__ int gposL[NB];
    __shared__ int partial[256];

    int t = threadIdx.x;

    if (blockIdx.x >= NCHB) {
        // weight-convert tail blocks
        int i = (blockIdx.x - NCHB) * 256 + t;
        if (i < 16384) {
            int n = i >> 7, k = i & 127;
            Wt0[i] = f2bf(W0[k * 128 + n]);
            Wt1[i] = f2bf(W1[k * 128 + n]);
        }
        if (i < 48 * 128) {
            int n = i >> 7, k = i & 127;
            Wt2[i] = (n < OUTD) ? f2bf(W2[k * OUTD + n]) : (unsigned short)0;
        }
        return;
    }

    int e0 = blockIdx.x * CHUNK;

    for (int i = t; i < NB; i += 256) cntL[i] = 0;
    __syncthreads();

    for (int i = t; i < CHUNK; i += 256) {
        int e = e0 + i;
        if (e < N_EDGES) atomicAdd(&cntL[dst[e] >> 7], 1);
    }
    __syncthreads();

    // exclusive scan of cntL[NB]
    int b4 = t * 4;
    int c0 = (b4 + 0 < NB) ? cntL[b4 + 0] : 0;
    int c1 = (b4 + 1 < NB) ? cntL[b4 + 1] : 0;
    int c2 = (b4 + 2 < NB) ? cntL[b4 + 2] : 0;
    int c3 = (b4 + 3 < NB) ? cntL[b4 + 3] : 0;
    int lsum = c0 + c1 + c2 + c3;
    partial[t] = lsum;
    __syncthreads();
    for (int off = 1; off < 256; off <<= 1) {
        int x = (t >= off) ? partial[t - off] : 0;
        __syncthreads();
        partial[t] += x;
        __syncthreads();
    }
    int pbase = partial[t] - lsum;
    if (b4 + 0 < NB) { excL[b4 + 0] = pbase;                curL[b4 + 0] = pbase; }
    if (b4 + 1 < NB) { excL[b4 + 1] = pbase + c0;           curL[b4 + 1] = pbase + c0; }
    if (b4 + 2 < NB) { excL[b4 + 2] = pbase + c0 + c1;      curL[b4 + 2] = pbase + c0 + c1; }
    if (b4 + 3 < NB) { excL[b4 + 3] = pbase + c0 + c1 + c2; curL[b4 + 3] = pbase + c0 + c1 + c2; }
    __syncthreads();

    int tot = partial[255];

    for (int i = t; i < CHUNK; i += 256) {
        int e = e0 + i;
        if (e < N_EDGES) {
            int d = dst[e];
            int s = src[e];
            int bkt = d >> 7;
            int pos = atomicAdd(&curL[bkt], 1);
            sortedL[pos] = ((unsigned int)s << 7) | (unsigned int)(d & 127);
            bucketOf[pos] = (unsigned short)bkt;
        }
    }
    __syncthreads();

    for (int b = t; b < NB; b += 256) {
        int c = cntL[b];
        gposL[b] = c ? atomicAdd(&gcur[b], c) : 0;
    }
    __syncthreads();

    for (int i = t; i < tot; i += 256) {
        unsigned int r = sortedL[i];
        int bkt = bucketOf[i];
        binned[(size_t)bkt * BCAP + gposL[bkt] + (i - excL[bkt])] = r;
    }
}

// ---------------- Phase B: per-fine-bucket CSR finalize into fixed regions ----------------

__global__ __launch_bounds__(256) void binB_k(
    const unsigned int* __restrict__ binned, const int* __restrict__ gcur,
    int2* __restrict__ rowse, float* __restrict__ dinv, int* __restrict__ colv)
{
    __shared__ unsigned int recL[BCAP];   // 10 KB
    __shared__ int colL[BCAP];            // 10 KB
    __shared__ int hist[2048];            // 8 KB: key = (localnode<<4) | src_chunk
    __shared__ int partial[256];

    int b = blockIdx.x, t = threadIdx.x;
    int cnt = gcur[b];
    int base = b * BCAP;
    const unsigned int* rp = binned + (size_t)b * BCAP;

    for (int i = t; i < 2048; i += 256) hist[i] = 0;
    __syncthreads();

    for (int i = t; i < cnt; i += 256) {
        unsigned int r = rp[i];
        recL[i] = r;
        unsigned int key = ((r & 127u) << 4) | src_chunk(r >> 7);
        atomicAdd(&hist[key], 1);
    }
    __syncthreads();

    // in-place exclusive scan of hist[2048]
    int base8 = t * 8;
    int v[8], lsum = 0;
#pragma unroll
    for (int j = 0; j < 8; j++) { v[j] = hist[base8 + j]; lsum += v[j]; }
    partial[t] = lsum;
    __syncthreads();
    for (int off = 1; off < 256; off <<= 1) {
        int x = (t >= off) ? partial[t - off] : 0;
        __syncthreads();
        partial[t] += x;
        __syncthreads();
    }
    int run = partial[t] - lsum;
#pragma unroll
    for (int j = 0; j < 8; j++) { hist[base8 + j] = run; run += v[j]; }
    __syncthreads();

    if (t < NPB) {
        int node = b * NPB + t;
        if (node < N_NODES) {
            int start = hist[t << 4];
            int end = (t < NPB - 1) ? hist[(t + 1) << 4] : cnt;
            rowse[node] = make_int2(base + start, base + end);
            dinv[node] = rsqrtf((float)(end - start + 1));   // +1 self-loop
        }
    }
    __syncthreads();

    for (int i = t; i < cnt; i += 256) {
        unsigned int r = recL[i];
        unsigned int key = ((r & 127u) << 4) | src_chunk(r >> 7);
        int pos = atomicAdd(&hist[key], 1);
        colL[pos] = (int)(r >> 7);
    }
    __syncthreads();
    for (int i = t; i < cnt; i += 256) colv[base + i] = colL[i];
}

// ---------------- MFMA GEMM (M x 128 @ 128 x N), fused BN-final+BN-apply+ReLU, dinv prescale ----------------

template <int ABF16, int MODE, int NT, int OBF16>
__global__ __launch_bounds__(256) void gemm_k(
    const void* __restrict__ Ap, const unsigned short* __restrict__ Wt,
    const float* __restrict__ bnSum, const float* __restrict__ bnSq,
    const float* __restrict__ gam, const float* __restrict__ bet,
    const float* __restrict__ dinv, void* __restrict__ Outp,
    int ncols, int ostride)
{
    __shared__ unsigned short WtL[NT * 16][136];
    __shared__ float sS[128], sT[128];

    int t = threadIdx.x;
    if (MODE) {
        if (t < 128) {
            float mean = bnSum[t] * (1.0f / N_NODES);
            float var = bnSq[t] * (1.0f / N_NODES) - mean * mean;
            float inv = rsqrtf(var + 1e-5f);
            float s = gam[t] * inv;
            sS[t] = s;
            sT[t] = bet[t] - mean * s;
        }
    }

    const int TOT = NT * 16 * 128;
    for (int e = t * 8; e < TOT; e += 256 * 8) {
        int n = e >> 7, k = e & 127;
        uint4 v = *(const uint4*)(Wt + e);
        *(uint4*)&WtL[n][k] = v;
    }
    __syncthreads();

    int wave = t >> 6, lane = t & 63;
    int quad = lane >> 4, m16 = lane & 15;
    int rbase = blockIdx.x * 128 + wave * 32;

    f32x4 acc[2][NT];
#pragma unroll
    for (int rt = 0; rt < 2; rt++)
#pragma unroll
        for (int ct = 0; ct < NT; ct++) acc[rt][ct] = (f32x4){0.f, 0.f, 0.f, 0.f};

#pragma unroll
    for (int kc = 0; kc < 4; kc++) {
        int kb = kc * 32 + quad * 8;
        bf16x8 afrag[2];
#pragma unroll
        for (int rt = 0; rt < 2; rt++) {
            int row = rbase + rt * 16 + m16;
            bool rv = (row < N_NODES);
            if (ABF16) {
                uint4 v = make_uint4(0, 0, 0, 0);
                if (rv) v = *(const uint4*)((const unsigned short*)Ap + (size_t)row * 128 + kb);
                if (MODE) {
                    unsigned int uu[4] = {v.x, v.y, v.z, v.w};
                    unsigned short* fp = (unsigned short*)&afrag[rt];
#pragma unroll
                    for (int i = 0; i < 4; i++) {
                        int k0 = kb + 2 * i;
                        float lo = fmaxf(bf_lo(uu[i]) * sS[k0] + sT[k0], 0.f);
                        float hi = fmaxf(bf_hi(uu[i]) * sS[k0 + 1] + sT[k0 + 1], 0.f);
                        fp[2 * i] = f2bf(lo);
                        fp[2 * i + 1] = f2bf(hi);
                    }
                } else {
                    afrag[rt] = *(bf16x8*)&v;
                }
            } else {
                const float* ap = (const float*)Ap + (size_t)row * 128 + kb;
                float4 f0 = make_float4(0.f, 0.f, 0.f, 0.f), f1 = f0;
                if (rv) { f0 = *(const float4*)ap; f1 = *(const float4*)(ap + 4); }
                unsigned short* fp = (unsigned short*)&afrag[rt];
                fp[0] = f2bf(f0.x); fp[1] = f2bf(f0.y); fp[2] = f2bf(f0.z); fp[3] = f2bf(f0.w);
                fp[4] = f2bf(f1.x); fp[5] = f2bf(f1.y); fp[6] = f2bf(f1.z); fp[7] = f2bf(f1.w);
            }
        }
#pragma unroll
        for (int ct = 0; ct < NT; ct++) {
            bf16x8 bfrag = *(bf16x8*)&WtL[ct * 16 + m16][kb];
#pragma unroll
            for (int rt = 0; rt < 2; rt++)
                acc[rt][ct] = __builtin_amdgcn_mfma_f32_16x16x32_bf16(
                    afrag[rt], bfrag, acc[rt][ct], 0, 0, 0);
        }
    }

#pragma unroll
    for (int rt = 0; rt < 2; rt++)
#pragma unroll
        for (int r = 0; r < 4; r++) {
            int row = rbase + rt * 16 + quad * 4 + r;
            if (row < N_NODES) {
                float d = dinv[row];
#pragma unroll
                for (int ct = 0; ct < NT; ct++) {
                    int c = ct * 16 + m16;
                    if (c < ncols) {
                        float val = acc[rt][ct][r] * d;
                        if (OBF16)
                            ((unsigned short*)Outp)[(size_t)row * ostride + c] = f2bf(val);
                        else
                            ((float*)Outp)[(size_t)row * ostride + c] = val;
                    }
                }
            }
        }
}

// ---------------- Aggregation: one wave per dst node, quarter-wave per record, uint4/lane ----------------

__global__ __launch_bounds__(256) void agg_k(
    const unsigned int* __restrict__ H, const int2* __restrict__ rowse,
    const int* __restrict__ colv, const float* __restrict__ dinv,
    const float* __restrict__ bias, unsigned int* __restrict__ out)
{
    int gw = (blockIdx.x * 256 + threadIdx.x) >> 6;
    int lane = threadIdx.x & 63;
    if (gw >= N_NODES) return;
    int q = lane >> 4;             // quarter id: records 4t+q
    int c = lane & 15;             // uint4 index within row (channels 8c..8c+7)
    int2 se = rowse[gw];
    int rp = se.x, re = se.y;
    const uint4* H4 = (const uint4*)H;   // row = 16 uint4 (256 B)

    float a0 = 0.f, a1 = 0.f, a2 = 0.f, a3 = 0.f;
    float a4 = 0.f, a5 = 0.f, a6 = 0.f, a7 = 0.f;
    if (q == 0) {                  // self-loop (prescaled row)
        uint4 u = H4[(size_t)gw * 16 + c];
        a0 = bf_lo(u.x); a1 = bf_hi(u.x); a2 = bf_lo(u.y); a3 = bf_hi(u.y);
        a4 = bf_lo(u.z); a5 = bf_hi(u.z); a6 = bf_lo(u.w); a7 = bf_hi(u.w);
    }

    for (int j0 = rp; j0 < re; j0 += 64) {
        int idx = (j0 + lane < re) ? colv[j0 + lane] : 0;
        int n = min(64, re - j0);
        int nq = n >> 2;           // complete groups of 4 records
        int t4 = 0;
        for (; t4 + 1 < nq; t4 += 2) {
            int sa = __shfl(idx, 4 * t4 + q);
            int sb = __shfl(idx, 4 * t4 + 4 + q);
            uint4 ua = H4[(size_t)sa * 16 + c];
            uint4 ub = H4[(size_t)sb * 16 + c];
            a0 += bf_lo(ua.x) + bf_lo(ub.x);
            a1 += bf_hi(ua.x) + bf_hi(ub.x);
            a2 += bf_lo(ua.y) + bf_lo(ub.y);
            a3 += bf_hi(ua.y) + bf_hi(ub.y);
            a4 += bf_lo(ua.z) + bf_lo(ub.z);
            a5 += bf_hi(ua.z) + bf_hi(ub.z);
            a6 += bf_lo(ua.w) + bf_lo(ub.w);
            a7 += bf_hi(ua.w) + bf_hi(ub.w);
        }
        if (t4 < nq) {
            int sa = __shfl(idx, 4 * t4 + q);
            uint4 ua = H4[(size_t)sa * 16 + c];
            a0 += bf_lo(ua.x); a1 += bf_hi(ua.x);
            a2 += bf_lo(ua.y); a3 += bf_hi(ua.y);
            a4 += bf_lo(ua.z); a5 += bf_hi(ua.z);
            a6 += bf_lo(ua.w); a7 += bf_hi(ua.w);
        }
        int rem = n & 3;           // tail records: quarters 0..rem-1
        if (rem) {
            int sa = __shfl(idx, (n - rem) + q);
            if (q < rem) {
                uint4 ua = H4[(size_t)sa * 16 + c];
                a0 += bf_lo(ua.x); a1 += bf_hi(ua.x);
                a2 += bf_lo(ua.y); a3 += bf_hi(ua.y);
                a4 += bf_lo(ua.z); a5 += bf_hi(ua.z);
                a6 += bf_lo(ua.w); a7 += bf_hi(ua.w);
            }
        }
    }

    // combine the four quarter accumulators
    a0 += __shfl_xor(a0, 16); a0 += __shfl_xor(a0, 32);
    a1 += __shfl_xor(a1, 16); a1 += __shfl_xor(a1, 32);
    a2 += __shfl_xor(a2, 16); a2 += __shfl_xor(a2, 32);
    a3 += __shfl_xor(a3, 16); a3 += __shfl_xor(a3, 32);
    a4 += __shfl_xor(a4, 16); a4 += __shfl_xor(a4, 32);
    a5 += __shfl_xor(a5, 16); a5 += __shfl_xor(a5, 32);
    a6 += __shfl_xor(a6, 16); a6 += __shfl_xor(a6, 32);
    a7 += __shfl_xor(a7, 16); a7 += __shfl_xor(a7, 32);

    if (q == 0) {
        float d = dinv[gw];
        float4 ba = ((const float4*)bias)[2 * c];
        float4 bb = ((const float4*)bias)[2 * c + 1];
        uint4 r;
        r.x = (unsigned int)f2bf(a0 * d + ba.x) | ((unsigned int)f2bf(a1 * d + ba.y) << 16);
        r.y = (unsigned int)f2bf(a2 * d + ba.z) | ((unsigned int)f2bf(a3 * d + ba.w) << 16);
        r.z = (unsigned int)f2bf(a4 * d + bb.x) | ((unsigned int)f2bf(a5 * d + bb.y) << 16);
        r.w = (unsigned int)f2bf(a6 * d + bb.z) | ((unsigned int)f2bf(a7 * d + bb.w) << 16);
        ((uint4*)out)[(size_t)gw * 16 + c] = r;
    }
}

// ---------------- Final aggregation (bf16 48-stride rows), quarter-wave + log_softmax ----------------

__global__ __launch_bounds__(256) void agg_out_k(
    const unsigned int* __restrict__ H, const int2* __restrict__ rowse,
    const int* __restrict__ colv, const float* __restrict__ dinv,
    const float* __restrict__ b2, float* __restrict__ out)
{
    int gw = (blockIdx.x * 256 + threadIdx.x) >> 6;
    int lane = threadIdx.x & 63;
    if (gw >= N_NODES) return;
    int q = lane >> 4;
    int c = lane & 15;
    bool ld = c < 12;              // 12 uint2 = 48 bf16 per row
    int2 se = rowse[gw];
    int rp = se.x, re = se.y;
    const uint2* H2 = (const uint2*)H;   // row = 12 uint2 (96 B)

    float a0 = 0.f, a1 = 0.f, a2 = 0.f, a3 = 0.f;
    if (q == 0 && ld) {
        uint2 u = H2[(size_t)gw * 12 + c];   // self (prescaled)
        a0 = bf_lo(u.x); a1 = bf_hi(u.x); a2 = bf_lo(u.y); a3 = bf_hi(u.y);
    }

    for (int j0 = rp; j0 < re; j0 += 64) {
        int idx = (j0 + lane < re) ? colv[j0 + lane] : 0;
        int n = min(64, re - j0);
        int nq = n >> 2;
        int t4 = 0;
        for (; t4 + 1 < nq; t4 += 2) {
            int sa = __shfl(idx, 4 * t4 + q);
            int sb = __shfl(idx, 4 * t4 + 4 + q);
            if (ld) {
                uint2 ua = H2[(size_t)sa * 12 + c];
                uint2 ub = H2[(size_t)sb * 12 + c];
                a0 += bf_lo(ua.x) + bf_lo(ub.x);
                a1 += bf_hi(ua.x) + bf_hi(ub.x);
                a2 += bf_lo(ua.y) + bf_lo(ub.y);
                a3 += bf_hi(ua.y) + bf_hi(ub.y);
            }
        }
        if (t4 < nq) {
            int sa = __shfl(idx, 4 * t4 + q);
            if (ld) {
                uint2 ua = H2[(size_t)sa * 12 + c];
                a0 += bf_lo(ua.x); a1 += bf_hi(ua.x);
                a2 += bf_lo(ua.y); a3 += bf_hi(ua.y);
            }
        }
        int rem = n & 3;
        if (rem) {
            int sa = __shfl(idx, (n - rem) + q);
            if (q < rem && ld) {
                uint2 ua = H2[(size_t)sa * 12 + c];
                a0 += bf_lo(ua.x); a1 += bf_hi(ua.x);
                a2 += bf_lo(ua.y); a3 += bf_hi(ua.y);
            }
        }
    }

    a0 += __shfl_xor(a0, 16); a0 += __shfl_xor(a0, 32);
    a1 += __shfl_xor(a1, 16); a1 += __shfl_xor(a1, 32);
    a2 += __shfl_xor(a2, 16); a2 += __shfl_xor(a2, 32);
    a3 += __shfl_xor(a3, 16); a3 += __shfl_xor(a3, 32);

    float d = dinv[gw];
    int ch = c * 4;
    float v0 = -INFINITY, v1 = -INFINITY, v2 = -INFINITY, v3 = -INFINITY;
    if (ld) {
        v0 = a0 * d + b2[ch];
        v1 = a1 * d + b2[ch + 1];
        v2 = a2 * d + b2[ch + 2];
        if (ch + 3 < OUTD) v3 = a3 * d + b2[ch + 3];
    }
    float m = fmaxf(fmaxf(v0, v1), fmaxf(v2, v3));
    m = fmaxf(m, __shfl_xor(m, 1));
    m = fmaxf(m, __shfl_xor(m, 2));
    m = fmaxf(m, __shfl_xor(m, 4));
    m = fmaxf(m, __shfl_xor(m, 8));
    float e = 0.f;
    if (ld) {
        e = __expf(v0 - m) + __expf(v1 - m) + __expf(v2 - m);
        if (ch + 3 < OUTD) e += __expf(v3 - m);
    }
    float sum = e;
    sum += __shfl_xor(sum, 1);
    sum += __shfl_xor(sum, 2);
    sum += __shfl_xor(sum, 4);
    sum += __shfl_xor(sum, 8);
    float ls = logf(sum);
    if (q == 0 && ld) {
        float* op = out + (size_t)gw * OUTD + ch;
        op[0] = v0 - m - ls;
        op[1] = v1 - m - ls;
        op[2] = v2 - m - ls;
        if (ch + 3 < OUTD) op[3] = v3 - m - ls;
    }
}

// ---------------- BatchNorm stats (bf16 input) ----------------

__global__ __launch_bounds__(256) void bnstats_k(const unsigned int* __restrict__ H,
                                                 float* __restrict__ sum,
                                                 float* __restrict__ sq)
{
    __shared__ float2 ls[256], lq[256];
    int t = threadIdx.x;
    int idx = blockIdx.x * 256 + t;
    int stride = gridDim.x * 256;
    float sx = 0.f, sy = 0.f, qx = 0.f, qy = 0.f;
    for (; idx < N_NODES * 64; idx += stride) {
        unsigned int u = H[idx];
        float x = bf_lo(u), y = bf_hi(u);
        sx += x; sy += y; qx += x * x; qy += y * y;
    }
    ls[t] = make_float2(sx, sy);
    lq[t] = make_float2(qx, qy);
    __syncthreads();
    if (t < 64) {
        float2 a = ls[t], b = ls[t + 64], c = ls[t + 128], d = ls[t + 192];
        float2 e = lq[t], f = lq[t + 64], g = lq[t + 128], h = lq[t + 192];
        int c0 = t * 2;
        atomicAdd(&sum[c0],     a.x + b.x + c.x + d.x);
        atomicAdd(&sum[c0 + 1], a.y + b.y + c.y + d.y);
        atomicAdd(&sq[c0],      e.x + f.x + g.x + h.x);
        atomicAdd(&sq[c0 + 1],  e.y + f.y + g.y + h.y);
    }
}

// ---------------- launch ----------------

extern "C" void kernel_launch(void* const* d_in, const int* in_sizes, int n_in,
                              void* d_out, int out_size, void* d_ws, size_t ws_size,
                              hipStream_t stream)
{
    const float* x   = (const float*)d_in[0];
    const int*   ei  = (const int*)d_in[1];
    const float* W0  = (const float*)d_in[2];
    const float* b0  = (const float*)d_in[3];
    const float* W1  = (const float*)d_in[4];
    const float* b1  = (const float*)d_in[5];
    const float* W2  = (const float*)d_in[6];
    const float* b2  = (const float*)d_in[7];
    const float* g0  = (const float*)d_in[8];
    const float* be0 = (const float*)d_in[9];
    const float* g1  = (const float*)d_in[10];
    const float* be1 = (const float*)d_in[11];
    const int* srcv = ei;
    const int* dstv = ei + N_EDGES;

    char* w = (char*)d_ws;
    unsigned int* H0 = (unsigned int*)w;  w += (size_t)N_NODES * 128 * 2;   // bf16 [N][128]
    unsigned int* H1 = (unsigned int*)w;  w += (size_t)N_NODES * 128 * 2;   // bf16 [N][128]
    unsigned int* Hf = (unsigned int*)w;  w += (size_t)N_NODES * OSTR * 2;  // bf16 [N][48]
    unsigned int* binned = (unsigned int*)w; w += (size_t)NB * BCAP * 4;    // 8.0 MB
    int* colv = (int*)w;        w += (size_t)NB * BCAP * 4;                 // 8.0 MB (fixed regions)
    unsigned short* Wt0 = (unsigned short*)w; w += 16384 * 2;
    unsigned short* Wt1 = (unsigned short*)w; w += 16384 * 2;
    unsigned short* Wt2 = (unsigned short*)w; w += 48 * 128 * 2;
    int2* rowse = (int2*)w;     w += (size_t)N_NODES * 8;
    float* dinv = (float*)w;    w += (size_t)N_NODES * 4;
    // single-memset region: gcur (784 ints) + bnS0,bnQ0,bnS1,bnQ1 (512 floats)
    int* gcur = (int*)w;        w += 784 * 4;
    float* bnS0 = (float*)w;    w += 128 * 4;
    float* bnQ0 = (float*)w;    w += 128 * 4;
    float* bnS1 = (float*)w;    w += 128 * 4;
    float* bnQ1 = (float*)w;    w += 128 * 4;

    int gb = (N_NODES + 127) / 128;       // 782
    int ab = (N_NODES * 64 + 255) / 256;  // 25000

    hipMemsetAsync(gcur, 0, (784 + 512) * 4, stream);

    binA_k<<<NCHB + CWB, 256, 0, stream>>>(srcv, dstv, gcur, binned,
                                           W0, W1, W2, Wt0, Wt1, Wt2);
    binB_k<<<NB, 256, 0, stream>>>(binned, gcur, rowse, dinv, colv);

    // Layer 0: x fp32 -> H0 bf16 (dinv-prescaled)
    gemm_k<0, 0, 8, 1><<<gb, 256, 0, stream>>>(x, Wt0, nullptr, nullptr, nullptr, nullptr,
                                               dinv, H0, 128, 128);
    agg_k<<<ab, 256, 0, stream>>>(H0, rowse, colv, dinv, b0, H1);
    bnstats_k<<<512, 256, 0, stream>>>(H1, bnS0, bnQ0);

    // Layer 1: BN-final+BN-apply+ReLU fused into gemm, bf16 MFMA
    gemm_k<1, 1, 8, 1><<<gb, 256, 0, stream>>>(H1, Wt1, bnS0, bnQ0, g0, be0,
                                               dinv, H0, 128, 128);
    agg_k<<<ab, 256, 0, stream>>>(H0, rowse, colv, dinv, b1, H1);
    bnstats_k<<<512, 256, 0, stream>>>(H1, bnS1, bnQ1);

    // Layer 2: 47-wide out (bf16, stride 48) + fused log_softmax aggregation
    gemm_k<1, 1, 3, 1><<<gb, 256, 0, stream>>>(H1, Wt2, bnS1, bnQ1, g1, be1,
                                               dinv, Hf, OUTD, OSTR);
    agg_out_k<<<ab, 256, 0, stream>>>(Hf, rowse, colv, dinv, b2, (float*)d_out);
}